// Round 17
// baseline (2060.545 us; speedup 1.0000x reference)
//
#include <hip/hip_runtime.h>
#include <hip/hip_bf16.h>
#include <stdint.h>

#define DDIM 768
#define NH 12
#define DHD 64
#define DFF 3072
#define NLAYER 12
#define SEQ 512
#define NB 8
#define ROWS (NB*SEQ)   // 4096

typedef __attribute__((ext_vector_type(4))) float f32x4;
typedef __attribute__((ext_vector_type(8))) short short8;

#define S_BARRIER()  asm volatile("s_barrier" ::: "memory")
#define WAIT_LGKM0() asm volatile("s_waitcnt lgkmcnt(0)" ::: "memory")
#define WAIT_VM0()   asm volatile("s_waitcnt vmcnt(0)" ::: "memory")
#define WAIT_VM3()   asm volatile("s_waitcnt vmcnt(3)" ::: "memory")
#define WAIT_VM4()   asm volatile("s_waitcnt vmcnt(4)" ::: "memory")

#define WDD    589824          // 768*768
#define WFD    2359296         // 3072*768

static __device__ __forceinline__ short bf16r(float f) {
  union { float f; uint32_t u; } a; a.f = f;
  uint32_t u = a.u;
  u += 0x7FFFu + ((u >> 16) & 1u);   // RNE
  return (short)(u >> 16);
}

static __device__ __forceinline__ float bf2f(short s) {
  union { uint32_t u; float f; } c;
  c.u = ((uint32_t)(uint16_t)s) << 16;
  return c.f;
}

static __device__ __forceinline__ f32x4 mfma_bf16(short8 a, short8 b, f32x4 c) {
  return __builtin_amdgcn_mfma_f32_16x16x32_bf16(a, b, c, 0, 0, 0);
}

// async global->LDS, 16B per lane. LDS dest is wave-uniform base; HW scatters
// lane i to base + i*16B. Global src is per-lane.
static __device__ __forceinline__ void gload16(const void* g, void* l) {
  __builtin_amdgcn_global_load_lds(
      (__attribute__((address_space(1))) void*)(void*)(uintptr_t)g,
      (__attribute__((address_space(3))) void*)l,
      16, 0, 0);
}

// ---------------------------------------------------------------------------
// fp32 -> bf16 conversion, up to 4 matrices per launch (grid.y selects matrix)
// ---------------------------------------------------------------------------
struct WCvt {
  const float* src[4];
  short* dst[4];
  int n8[4];
};

__global__ void wconv_kernel(WCvt wc) {
  const int m = blockIdx.y;
  const float* __restrict__ src = wc.src[m];
  short* __restrict__ dst = wc.dst[m];
  const int n8 = wc.n8[m];
  for (int i = blockIdx.x * 256 + threadIdx.x; i < n8; i += gridDim.x * 256) {
    f32x4 a = *(const f32x4*)(src + (size_t)i * 8);
    f32x4 b = *(const f32x4*)(src + (size_t)i * 8 + 4);
    short8 o;
    o[0] = bf16r(a[0]); o[1] = bf16r(a[1]); o[2] = bf16r(a[2]); o[3] = bf16r(a[3]);
    o[4] = bf16r(b[0]); o[5] = bf16r(b[1]); o[6] = bf16r(b[2]); o[7] = bf16r(b[3]);
    *(short8*)(dst + (size_t)i * 8) = o;
  }
}

// ---------------------------------------------------------------------------
// GEMM: C[M,N] = A[M,K] @ W[N,K]^T + bias   (bf16 in, fp32 acc)
// OUTMODE: 1 = bf16 out (+bias), 2 = bf16 out (+bias, ReLU),
//          3 = fp32 PARTIAL out (no bias; split-K half)
// BM x 128 tile, BK=32, 256 threads (4 waves, 2x2 wave grid).
// Counted-vmcnt pipeline (T4): depth-2 prefetch over 2 LDS buffers.
// SPLITK=1: blockIdx.z = K-half (Klen = K/2, Kstride = full K); partials to
// o0/o1 (3 blk/CU vs 1.5 -> R15's measured -131 us win).
// SPLITK=0: blockIdx.z selects (W, bias, out) triple (fused QKV).
// ---------------------------------------------------------------------------
struct GemmB {
  const short* W0; const short* W1; const short* W2;
  const float* b0; const float* b1; const float* b2;
  void* o0; void* o1; void* o2;
};

template<int OUTMODE, int BM, int SPLITK>
__launch_bounds__(256, 3)
__global__ void gemm_bt(const short* __restrict__ A, GemmB gb,
                        int M, int N, int Kstride, int Klen) {
  constexpr int MF  = BM / 32;   // row fragments per wave (4 or 2)
  constexpr int ISS = BM / 64;   // A staging issues per wave (2 or 1)

  const int z = blockIdx.z;
  const short* W;
  const float* bias;
  void* outp;
  if (SPLITK) {
    W    = gb.W0 + (size_t)z * Klen;       // column offset within each row
    bias = gb.b0;                          // unused (OUTMODE 3)
    outp = (z == 0) ? gb.o0 : gb.o1;
  } else {
    W    = (z == 0) ? gb.W0 : ((z == 1) ? gb.W1 : gb.W2);
    bias = (z == 0) ? gb.b0 : ((z == 1) ? gb.b1 : gb.b2);
    outp = (z == 0) ? gb.o0 : ((z == 1) ? gb.o1 : gb.o2);
  }

  __shared__ __align__(16) short As[2][BM * 32];
  __shared__ __align__(16) short Bs[2][128 * 32];

  const int tid  = threadIdx.x;
  const int lane = tid & 63;
  const int wid  = tid >> 6;
  const int l16  = lane & 15;
  const int kg   = lane >> 4;
  const int wr   = wid >> 1;
  const int wc   = wid & 1;
  const int m0   = blockIdx.x * BM;
  const int n0   = blockIdx.y * 128;

  const f32x4 zero = {0.f, 0.f, 0.f, 0.f};
  f32x4 acc[MF][4];
  #pragma unroll
  for (int i = 0; i < MF; i++)
    #pragma unroll
    for (int j = 0; j < 4; j++) acc[i][j] = zero;

  // staging: per issue, one wave covers 16 rows (64 lanes x 16B; 4 lanes/row)
  const int lrow = lane >> 2;          // 0..15
  const int lcol = (lane & 3) * 8;     // short offset within row
  const short* Ag = A + (size_t)(m0 + wid * (BM / 4) + lrow) * Kstride + lcol
                      + (SPLITK ? (size_t)z * Klen : 0);
  const short* Wg = W + (size_t)(n0 + wid * 32 + lrow) * Kstride + lcol;

  auto stage = [&](int buf, int k0) {
    #pragma unroll
    for (int j = 0; j < ISS; j++)
      gload16(Ag + k0 + (size_t)(j * 16) * Kstride, &As[buf][(wid * (BM / 4) + j * 16) * 32]);
    #pragma unroll
    for (int j = 0; j < 2; j++)
      gload16(Wg + k0 + (size_t)(j * 16) * Kstride, &Bs[buf][(wid * 32 + j * 16) * 32]);
  };

  const int nsteps = Klen >> 5;        // 12, 24, 48 or 96
  stage(0, 0);
  stage(1, 32);
  if (ISS == 2) { WAIT_VM4(); } else { WAIT_VM3(); }
  S_BARRIER();

  for (int t = 0; t < nsteps; ++t) {
    const int cur = t & 1;
    short8 af[MF], bfr[4];
    #pragma unroll
    for (int i = 0; i < MF; i++)
      af[i] = *(const short8*)&As[cur][(wr * (BM / 2) + i * 16 + l16) * 32 + kg * 8];
    #pragma unroll
    for (int j = 0; j < 4; j++)
      bfr[j] = *(const short8*)&Bs[cur][(wc * 64 + j * 16 + l16) * 32 + kg * 8];
    WAIT_LGKM0();                       // my reads of buf[cur] complete
    S_BARRIER();                        // all waves' reads complete -> reusable

    const bool pf = (t + 2 < nsteps);
    if (pf) stage(cur, (t + 2) << 5);   // overwrite consumed buffer
    __builtin_amdgcn_sched_barrier(0);  // MFMA stays after the stage issue
    #pragma unroll
    for (int i = 0; i < MF; i++)
      #pragma unroll
      for (int j = 0; j < 4; j++)
        acc[i][j] = mfma_bf16(af[i], bfr[j], acc[i][j]);
    __builtin_amdgcn_sched_barrier(0);  // MFMA stays before the vmcnt wait

    if (pf) { if (ISS == 2) { WAIT_VM4(); } else { WAIT_VM3(); } }
    else    { WAIT_VM0(); }             // tail: drain remaining loads
    S_BARRIER();                        // tile t+1 ready for all waves
  }

  float* outf = (float*)outp;
  short* outb = (short*)outp;
  #pragma unroll
  for (int j = 0; j < 4; j++) {
    const int col = n0 + wc * 64 + j * 16 + l16;
    const float bv = (OUTMODE == 3) ? 0.0f : bias[col];
    #pragma unroll
    for (int i = 0; i < MF; i++) {
      const int row0 = m0 + wr * (BM / 2) + i * 16 + kg * 4;
      #pragma unroll
      for (int e = 0; e < 4; e++) {
        float v = acc[i][j][e] + bv;
        if (OUTMODE == 2) v = fmaxf(v, 0.0f);
        const size_t off = (size_t)(row0 + e) * N + col;
        if (OUTMODE == 3) outf[off] = v;
        else              outb[off] = bf16r(v);
      }
    }
  }
}

// ---------------------------------------------------------------------------
// Fused flash attention. Block = 256 threads (4 waves), grid = (B*H, S/64).
// R17: each wave owns 16 q rows (was 32) -> 768 blocks vs 2-resident LDS cap
// (was 384 = half the CUs single-block). V^T staged in LDS (64KB, XOR
// swizzle). Swapped QK^T: softmax stats lane-local per q column.
// ---------------------------------------------------------------------------
__launch_bounds__(256, 2)
__global__ void attn_kernel(const short* __restrict__ Qg, const short* __restrict__ Kg,
                            const short* __restrict__ Vg, const float* __restrict__ mask,
                            short* __restrict__ ctx) {
  __shared__ __align__(16) short Vt[64 * 512];   // [d][kv^swz], 64 KiB

  const int bh = blockIdx.x;            // 0..95
  const int b = bh / NH;
  const int h = bh % NH;
  const int tid  = threadIdx.x;
  const int lane = tid & 63;
  const int wid  = tid >> 6;
  const int l16  = lane & 15;
  const int kg   = lane >> 4;

  const short* Qb = Qg + (size_t)b * SEQ * DDIM + h * DHD;
  const short* Kb = Kg + (size_t)b * SEQ * DDIM + h * DHD;
  const short* Vb = Vg + (size_t)b * SEQ * DDIM + h * DHD;

  // stage V^T: Vt[d][kv ^ ((d&3)<<3)] = V[kv][d]
  for (int c = tid; c < SEQ * 8; c += 256) {
    const int kv = c >> 3;
    const int d0 = (c & 7) * 8;
    short8 v = *(const short8*)(Vb + (size_t)kv * DDIM + d0);
    #pragma unroll
    for (int j = 0; j < 8; j++)
      Vt[(d0 + j) * 512 + (kv ^ ((j & 3) << 3))] = v[j];
  }
  __syncthreads();

  const int q0 = blockIdx.y * 64 + wid * 16;

  // Q fragments (B operand: lane holds col q = l16, elems d = kg*8+j)
  short8 qf[2];
  #pragma unroll
  for (int dh = 0; dh < 2; dh++)
    qf[dh] = *(const short8*)(Qb + (size_t)(q0 + l16) * DDIM + dh * 32 + kg * 8);

  float mrun = -1e30f;
  float lrun = 0.0f;
  const f32x4 zero = {0.f, 0.f, 0.f, 0.f};
  f32x4 oacc[4];
  #pragma unroll
  for (int dt = 0; dt < 4; dt++) oacc[dt] = zero;

  const float* maskb = mask + (size_t)b * SEQ;

  for (int kv0 = 0; kv0 < SEQ; kv0 += 32) {
    // K fragments (A operand: lane holds row kv, elems d)
    short8 kf[2][2];
    #pragma unroll
    for (int kvh = 0; kvh < 2; kvh++)
      #pragma unroll
      for (int dh = 0; dh < 2; dh++)
        kf[kvh][dh] = *(const short8*)(Kb + (size_t)(kv0 + kvh * 16 + l16) * DDIM + dh * 32 + kg * 8);

    // V fragments (B operand of PV): lane holds col d = dt*16+l16, elems kv = kg*8+j
    short8 vf[4];
    #pragma unroll
    for (int dt = 0; dt < 4; dt++) {
      const int d = dt * 16 + l16;
      vf[dt] = *(const short8*)&Vt[d * 512 + ((kv0 + kg * 8) ^ ((d & 3) << 3))];
    }

    const f32x4 mq0 = *(const f32x4*)(maskb + kv0 + kg * 4);
    const f32x4 mq1 = *(const f32x4*)(maskb + kv0 + 16 + kg * 4);

    f32x4 s0 = zero, s1 = zero;
    s0 = mfma_bf16(kf[0][0], qf[0], s0);
    s0 = mfma_bf16(kf[0][1], qf[1], s0);
    s1 = mfma_bf16(kf[1][0], qf[0], s1);
    s1 = mfma_bf16(kf[1][1], qf[1], s1);

    float p[8];
    #pragma unroll
    for (int e = 0; e < 4; e++) {
      p[e]     = s0[e] * 0.125f + mq0[e] * (-1e9f);
      p[e + 4] = s1[e] * 0.125f + mq1[e] * (-1e9f);
    }
    float mt = p[0];
    #pragma unroll
    for (int e = 1; e < 8; e++) mt = fmaxf(mt, p[e]);
    mt = fmaxf(mt, __shfl_xor(mt, 16, 64));
    mt = fmaxf(mt, __shfl_xor(mt, 32, 64));
    const float mnew = fmaxf(mrun, mt);
    const float corr = __expf(mrun - mnew);
    float ts = 0.0f;
    #pragma unroll
    for (int e = 0; e < 8; e++) { p[e] = __expf(p[e] - mnew); ts += p[e]; }
    ts += __shfl_xor(ts, 16, 64);
    ts += __shfl_xor(ts, 32, 64);
    lrun = lrun * corr + ts;
    mrun = mnew;

    // pack p to bf16 pairs; redistribute to A-operand layout via shuffles
    const int P0 = (int)(((uint32_t)(uint16_t)bf16r(p[1]) << 16) | (uint16_t)bf16r(p[0]));
    const int P1 = (int)(((uint32_t)(uint16_t)bf16r(p[3]) << 16) | (uint16_t)bf16r(p[2]));
    const int P2 = (int)(((uint32_t)(uint16_t)bf16r(p[5]) << 16) | (uint16_t)bf16r(p[4]));
    const int P3 = (int)(((uint32_t)(uint16_t)bf16r(p[7]) << 16) | (uint16_t)bf16r(p[6]));
    const int sl0 = (((2 * kg) & 3) << 4) + l16;
    const int sl1 = (((2 * kg + 1) & 3) << 4) + l16;
    const int x0 = __shfl(P0, sl0, 64), y0 = __shfl(P2, sl0, 64);
    const int x1 = __shfl(P1, sl0, 64), y1 = __shfl(P3, sl0, 64);
    const int x2 = __shfl(P0, sl1, 64), y2 = __shfl(P2, sl1, 64);
    const int x3 = __shfl(P1, sl1, 64), y3 = __shfl(P3, sl1, 64);
    union { int w[4]; short8 v; } pa;
    const bool hi = (kg >= 2);
    pa.w[0] = hi ? y0 : x0;
    pa.w[1] = hi ? y1 : x1;
    pa.w[2] = hi ? y2 : x2;
    pa.w[3] = hi ? y3 : x3;

    // per-q-row rescale factors for O acc (O rows q = kg*4+e)
    const float c0 = __shfl(corr, kg * 4 + 0, 64);
    const float c1 = __shfl(corr, kg * 4 + 1, 64);
    const float c2 = __shfl(corr, kg * 4 + 2, 64);
    const float c3 = __shfl(corr, kg * 4 + 3, 64);

    #pragma unroll
    for (int dt = 0; dt < 4; dt++) {
      f32x4 o = oacc[dt];
      o[0] *= c0; o[1] *= c1; o[2] *= c2; o[3] *= c3;
      oacc[dt] = mfma_bf16(pa.v, vf[dt], o);
    }
  }

  short* cb = ctx + (size_t)b * SEQ * DDIM + h * DHD;
  {
    const float li = 1.0f / lrun;
    const float l0 = __shfl(li, kg * 4 + 0, 64);
    const float l1 = __shfl(li, kg * 4 + 1, 64);
    const float l2 = __shfl(li, kg * 4 + 2, 64);
    const float l3 = __shfl(li, kg * 4 + 3, 64);
    #pragma unroll
    for (int dt = 0; dt < 4; dt++) {
      const f32x4 o = oacc[dt];
      const int col = dt * 16 + l16;
      const size_t base = (size_t)(q0 + kg * 4) * DDIM + col;
      cb[base + 0 * DDIM] = bf16r(o[0] * l0);
      cb[base + 1 * DDIM] = bf16r(o[1] * l1);
      cb[base + 2 * DDIM] = bf16r(o[2] * l2);
      cb[base + 3 * DDIM] = bf16r(o[3] * l3);
    }
  }
}

// ---------------------------------------------------------------------------
// Fused split-K reduce + LayerNorm:
// y = LN(resid + p0 + p1 + pbias) -> fp32 out + bf16 out.
// One wave per row (768 = 12 elems/lane). In-place safe (reads before writes).
// ---------------------------------------------------------------------------
__launch_bounds__(256, 4)
__global__ void ln_red_kernel(const float* __restrict__ resid,
                              const float* __restrict__ p0,
                              const float* __restrict__ p1,
                              const float* __restrict__ pb,
                              const float* __restrict__ gw,
                              const float* __restrict__ bw,
                              float* __restrict__ outf, short* __restrict__ outb) {
  const int lane = threadIdx.x & 63;
  const int wid  = threadIdx.x >> 6;
  const int row  = blockIdx.x * 4 + wid;
  const size_t base = (size_t)row * DDIM;
  float v[12];
  float s = 0.0f;
  #pragma unroll
  for (int c = 0; c < 12; c++) {
    const int idx = c * 64 + lane;
    v[c] = resid[base + idx] + p0[base + idx] + p1[base + idx] + pb[idx];
    s += v[c];
  }
  #pragma unroll
  for (int o = 1; o < 64; o <<= 1) s += __shfl_xor(s, o, 64);
  const float mean = s * (1.0f / 768.0f);
  float q = 0.0f;
  #pragma unroll
  for (int c = 0; c < 12; c++) { const float d = v[c] - mean; q += d * d; }
  #pragma unroll
  for (int o = 1; o < 64; o <<= 1) q += __shfl_xor(q, o, 64);
  const float inv = 1.0f / sqrtf(q * (1.0f / 768.0f) + 1e-5f);
  #pragma unroll
  for (int c = 0; c < 12; c++) {
    const int idx = c * 64 + lane;
    const float y = gw[idx] * (v[c] - mean) * inv + bw[idx];
    outf[base + idx] = y;
    outb[base + idx] = bf16r(y);
  }
}

// ---------------------------------------------------------------------------
// Workspace (~79 MB):
//   H0   fp32 [4096][768]  residual stream (in-place LN)
//   Bbuf bf16 [4096][768]  bf16 of h / a
//   R1   bf16 [4096][3072] quarters: Q,K,V,ctx -> ffn1 full
//   WB   bf16 2*WFD        phase A: Wq,Wk,Wv,Wo ; phase B: W1,W2
//   P0,P1 fp32 [4096][768] split-K partial outputs (Oproj / FFN2)
// ---------------------------------------------------------------------------
extern "C" void kernel_launch(void* const* d_in, const int* in_sizes, int n_in,
                              void* d_out, int out_size, void* d_ws, size_t ws_size,
                              hipStream_t stream) {
  const float* x    = (const float*)d_in[0];
  const float* mask = (const float*)d_in[1];
  const float* Wq   = (const float*)d_in[2];
  const float* bq   = (const float*)d_in[3];
  const float* Wk   = (const float*)d_in[4];
  const float* bk   = (const float*)d_in[5];
  const float* Wv   = (const float*)d_in[6];
  const float* bv   = (const float*)d_in[7];
  const float* Wo   = (const float*)d_in[8];
  const float* bo   = (const float*)d_in[9];
  const float* g1   = (const float*)d_in[10];
  const float* b1   = (const float*)d_in[11];
  const float* W1   = (const float*)d_in[12];
  const float* bf1  = (const float*)d_in[13];
  const float* W2   = (const float*)d_in[14];
  const float* bf2  = (const float*)d_in[15];
  const float* g2   = (const float*)d_in[16];
  const float* b2   = (const float*)d_in[17];

  const size_t SD = (size_t)ROWS * DDIM;   // 3145728

  char* ws = (char*)d_ws;
  float* H0   = (float*)ws;  ws += SD * 4;                 // 12.58 MB
  short* Bbuf = (short*)ws;  ws += SD * 2;                 //  6.29 MB
  short* R1   = (short*)ws;  ws += (size_t)ROWS * DFF * 2; // 25.17 MB
  short* WB   = (short*)ws;  ws += (size_t)2 * WFD * 2;    //  9.44 MB
  float* P0   = (float*)ws;  ws += SD * 4;                 // 12.58 MB
  float* P1   = (float*)ws;                                // 12.58 MB

  short* Qb = R1;
  short* Kb = R1 + SD;
  short* Vb = R1 + 2 * SD;
  short* Cb = R1 + 3 * SD;

  // x -> bf16
  {
    WCvt c{};
    c.src[0] = x; c.dst[0] = Bbuf; c.n8[0] = (int)(SD / 8);
    wconv_kernel<<<dim3(1536, 1), 256, 0, stream>>>(c);
  }

  for (int l = 0; l < NLAYER; l++) {
    // phase A weights: Wq,Wk,Wv,Wo
    {
      WCvt c{};
      c.src[0] = Wq + (size_t)l * WDD; c.dst[0] = WB;           c.n8[0] = (int)(WDD / 8);
      c.src[1] = Wk + (size_t)l * WDD; c.dst[1] = WB + WDD;     c.n8[1] = (int)(WDD / 8);
      c.src[2] = Wv + (size_t)l * WDD; c.dst[2] = WB + 2 * WDD; c.n8[2] = (int)(WDD / 8);
      c.src[3] = Wo + (size_t)l * WDD; c.dst[3] = WB + 3 * WDD; c.n8[3] = (int)(WDD / 8);
      wconv_kernel<<<dim3(288, 4), 256, 0, stream>>>(c);
    }

    // QKV (fused via grid.z)
    {
      GemmB g{};
      g.W0 = WB;           g.b0 = bq + (size_t)l * DDIM; g.o0 = Qb;
      g.W1 = WB + WDD;     g.b1 = bk + (size_t)l * DDIM; g.o1 = Kb;
      g.W2 = WB + 2 * WDD; g.b2 = bv + (size_t)l * DDIM; g.o2 = Vb;
      gemm_bt<1, 128, 0><<<dim3(32, 6, 3), 256, 0, stream>>>(Bbuf, g, ROWS, DDIM, DDIM, DDIM);
    }

    // attention: ctx -> q3 (768 blocks, 16 q-rows per wave)
    attn_kernel<<<dim3(NB * NH, 8), 256, 0, stream>>>(Qb, Kb, Vb, mask, Cb);

    // O projection, split-K2 -> P0,P1 (768 blocks = 3/CU)
    {
      GemmB g{};
      g.W0 = WB + 3 * WDD; g.b0 = bo; g.o0 = P0; g.o1 = P1;
      gemm_bt<3, 64, 1><<<dim3(64, 6, 2), 256, 0, stream>>>(Cb, g, ROWS, DDIM, DDIM, DDIM / 2);
    }

    // LN1 = reduce(P0+P1) + bias + LN(h + .) -> H0 (fp32) + Bbuf (bf16)
    ln_red_kernel<<<dim3(ROWS / 4), 256, 0, stream>>>(l ? H0 : x, P0, P1,
                                                      bo + (size_t)l * DDIM,
                                                      g1 + (size_t)l * DDIM, b1 + (size_t)l * DDIM,
                                                      H0, Bbuf);

    // phase B weights: W1,W2
    {
      WCvt c{};
      c.src[0] = W1 + (size_t)l * WFD; c.dst[0] = WB;       c.n8[0] = (int)(WFD / 8);
      c.src[1] = W2 + (size_t)l * WFD; c.dst[1] = WB + WFD; c.n8[1] = (int)(WFD / 8);
      wconv_kernel<<<dim3(1152, 2), 256, 0, stream>>>(c);
    }

    // FFN1 (bf16 + ReLU) -> R1 full
    {
      GemmB g{};
      g.W0 = WB; g.b0 = bf1 + (size_t)l * DFF; g.o0 = R1;
      gemm_bt<2, 128, 0><<<dim3(32, 24, 1), 256, 0, stream>>>(Bbuf, g, ROWS, DFF, DDIM, DDIM);
    }

    // FFN2, split-K2 -> P0,P1 (768 blocks, 48 steps each)
    {
      GemmB g{};
      g.W0 = WB + WFD; g.b0 = bf2; g.o0 = P0; g.o1 = P1;
      gemm_bt<3, 64, 1><<<dim3(64, 6, 2), 256, 0, stream>>>(R1, g, ROWS, DDIM, DFF, DFF / 2);
    }

    // LN2 = reduce(P0+P1) + bias + LN(a + .) -> H0 / d_out (fp32) + Bbuf (bf16)
    ln_red_kernel<<<dim3(ROWS / 4), 256, 0, stream>>>(H0, P0, P1,
                                                      bf2 + (size_t)l * DDIM,
                                                      g2 + (size_t)l * DDIM, b2 + (size_t)l * DDIM,
                                                      (l == NLAYER - 1) ? (float*)d_out : H0,
                                                      Bbuf);
  }
}

// Round 18
// 1968.668 us; speedup vs baseline: 1.0467x; 1.0467x over previous
//
#include <hip/hip_runtime.h>
#include <hip/hip_bf16.h>
#include <stdint.h>

#define DDIM 768
#define NH 12
#define DHD 64
#define DFF 3072
#define NLAYER 12
#define SEQ 512
#define NB 8
#define ROWS (NB*SEQ)   // 4096

typedef __attribute__((ext_vector_type(4))) float f32x4;
typedef __attribute__((ext_vector_type(8))) short short8;

#define S_BARRIER()  asm volatile("s_barrier" ::: "memory")
#define WAIT_LGKM0() asm volatile("s_waitcnt lgkmcnt(0)" ::: "memory")
#define WAIT_VM0()   asm volatile("s_waitcnt vmcnt(0)" ::: "memory")
#define WAIT_VM3()   asm volatile("s_waitcnt vmcnt(3)" ::: "memory")
#define WAIT_VM4()   asm volatile("s_waitcnt vmcnt(4)" ::: "memory")

#define WDD    589824          // 768*768
#define WFD    2359296         // 3072*768

static __device__ __forceinline__ short bf16r(float f) {
  union { float f; uint32_t u; } a; a.f = f;
  uint32_t u = a.u;
  u += 0x7FFFu + ((u >> 16) & 1u);   // RNE
  return (short)(u >> 16);
}

static __device__ __forceinline__ float bf2f(short s) {
  union { uint32_t u; float f; } c;
  c.u = ((uint32_t)(uint16_t)s) << 16;
  return c.f;
}

static __device__ __forceinline__ f32x4 mfma_bf16(short8 a, short8 b, f32x4 c) {
  return __builtin_amdgcn_mfma_f32_16x16x32_bf16(a, b, c, 0, 0, 0);
}

// async global->LDS, 16B per lane. LDS dest is wave-uniform base; HW scatters
// lane i to base + i*16B. Global src is per-lane.
static __device__ __forceinline__ void gload16(const void* g, void* l) {
  __builtin_amdgcn_global_load_lds(
      (__attribute__((address_space(1))) void*)(void*)(uintptr_t)g,
      (__attribute__((address_space(3))) void*)l,
      16, 0, 0);
}

// ---------------------------------------------------------------------------
// fp32 -> bf16 conversion, up to 4 matrices per launch (grid.y selects matrix)
// ---------------------------------------------------------------------------
struct WCvt {
  const float* src[4];
  short* dst[4];
  int n8[4];
};

__global__ void wconv_kernel(WCvt wc) {
  const int m = blockIdx.y;
  const float* __restrict__ src = wc.src[m];
  short* __restrict__ dst = wc.dst[m];
  const int n8 = wc.n8[m];
  for (int i = blockIdx.x * 256 + threadIdx.x; i < n8; i += gridDim.x * 256) {
    f32x4 a = *(const f32x4*)(src + (size_t)i * 8);
    f32x4 b = *(const f32x4*)(src + (size_t)i * 8 + 4);
    short8 o;
    o[0] = bf16r(a[0]); o[1] = bf16r(a[1]); o[2] = bf16r(a[2]); o[3] = bf16r(a[3]);
    o[4] = bf16r(b[0]); o[5] = bf16r(b[1]); o[6] = bf16r(b[2]); o[7] = bf16r(b[3]);
    *(short8*)(dst + (size_t)i * 8) = o;
  }
}

// ---------------------------------------------------------------------------
// GEMM: C[M,N] = A[M,K] @ W[N,K]^T + bias   (bf16 in, fp32 acc)
// OUTMODE: 1 = bf16 out (+bias), 2 = bf16 out (+bias, ReLU),
//          3 = fp32 PARTIAL out (no bias; split-K half)
// BM x 128 tile, BK=32, 256 threads (4 waves, 2x2 wave grid).
// Counted-vmcnt pipeline (T4): depth-2 prefetch over 2 LDS buffers.
// SPLITK=1: blockIdx.z = K-half (Klen = K/2, Kstride = full K); partials to
// o0/o1 (3 blk/CU vs 1.5 -> R15's measured -131 us win).
// SPLITK=0: blockIdx.z selects (W, bias, out) triple (fused QKV).
// ---------------------------------------------------------------------------
struct GemmB {
  const short* W0; const short* W1; const short* W2;
  const float* b0; const float* b1; const float* b2;
  void* o0; void* o1; void* o2;
};

template<int OUTMODE, int BM, int SPLITK>
__launch_bounds__(256, 3)
__global__ void gemm_bt(const short* __restrict__ A, GemmB gb,
                        int M, int N, int Kstride, int Klen) {
  constexpr int MF  = BM / 32;   // row fragments per wave (4 or 2)
  constexpr int ISS = BM / 64;   // A staging issues per wave (2 or 1)

  const int z = blockIdx.z;
  const short* W;
  const float* bias;
  void* outp;
  if (SPLITK) {
    W    = gb.W0 + (size_t)z * Klen;       // column offset within each row
    bias = gb.b0;                          // unused (OUTMODE 3)
    outp = (z == 0) ? gb.o0 : gb.o1;
  } else {
    W    = (z == 0) ? gb.W0 : ((z == 1) ? gb.W1 : gb.W2);
    bias = (z == 0) ? gb.b0 : ((z == 1) ? gb.b1 : gb.b2);
    outp = (z == 0) ? gb.o0 : ((z == 1) ? gb.o1 : gb.o2);
  }

  __shared__ __align__(16) short As[2][BM * 32];
  __shared__ __align__(16) short Bs[2][128 * 32];

  const int tid  = threadIdx.x;
  const int lane = tid & 63;
  const int wid  = tid >> 6;
  const int l16  = lane & 15;
  const int kg   = lane >> 4;
  const int wr   = wid >> 1;
  const int wc   = wid & 1;
  const int m0   = blockIdx.x * BM;
  const int n0   = blockIdx.y * 128;

  const f32x4 zero = {0.f, 0.f, 0.f, 0.f};
  f32x4 acc[MF][4];
  #pragma unroll
  for (int i = 0; i < MF; i++)
    #pragma unroll
    for (int j = 0; j < 4; j++) acc[i][j] = zero;

  // staging: per issue, one wave covers 16 rows (64 lanes x 16B; 4 lanes/row)
  const int lrow = lane >> 2;          // 0..15
  const int lcol = (lane & 3) * 8;     // short offset within row
  const short* Ag = A + (size_t)(m0 + wid * (BM / 4) + lrow) * Kstride + lcol
                      + (SPLITK ? (size_t)z * Klen : 0);
  const short* Wg = W + (size_t)(n0 + wid * 32 + lrow) * Kstride + lcol;

  auto stage = [&](int buf, int k0) {
    #pragma unroll
    for (int j = 0; j < ISS; j++)
      gload16(Ag + k0 + (size_t)(j * 16) * Kstride, &As[buf][(wid * (BM / 4) + j * 16) * 32]);
    #pragma unroll
    for (int j = 0; j < 2; j++)
      gload16(Wg + k0 + (size_t)(j * 16) * Kstride, &Bs[buf][(wid * 32 + j * 16) * 32]);
  };

  const int nsteps = Klen >> 5;        // 12, 24, 48 or 96
  stage(0, 0);
  stage(1, 32);
  if (ISS == 2) { WAIT_VM4(); } else { WAIT_VM3(); }
  S_BARRIER();

  for (int t = 0; t < nsteps; ++t) {
    const int cur = t & 1;
    short8 af[MF], bfr[4];
    #pragma unroll
    for (int i = 0; i < MF; i++)
      af[i] = *(const short8*)&As[cur][(wr * (BM / 2) + i * 16 + l16) * 32 + kg * 8];
    #pragma unroll
    for (int j = 0; j < 4; j++)
      bfr[j] = *(const short8*)&Bs[cur][(wc * 64 + j * 16 + l16) * 32 + kg * 8];
    WAIT_LGKM0();                       // my reads of buf[cur] complete
    S_BARRIER();                        // all waves' reads complete -> reusable

    const bool pf = (t + 2 < nsteps);
    if (pf) stage(cur, (t + 2) << 5);   // overwrite consumed buffer
    __builtin_amdgcn_sched_barrier(0);  // MFMA stays after the stage issue
    #pragma unroll
    for (int i = 0; i < MF; i++)
      #pragma unroll
      for (int j = 0; j < 4; j++)
        acc[i][j] = mfma_bf16(af[i], bfr[j], acc[i][j]);
    __builtin_amdgcn_sched_barrier(0);  // MFMA stays before the vmcnt wait

    if (pf) { if (ISS == 2) { WAIT_VM4(); } else { WAIT_VM3(); } }
    else    { WAIT_VM0(); }             // tail: drain remaining loads
    S_BARRIER();                        // tile t+1 ready for all waves
  }

  float* outf = (float*)outp;
  short* outb = (short*)outp;
  #pragma unroll
  for (int j = 0; j < 4; j++) {
    const int col = n0 + wc * 64 + j * 16 + l16;
    const float bv = (OUTMODE == 3) ? 0.0f : bias[col];
    #pragma unroll
    for (int i = 0; i < MF; i++) {
      const int row0 = m0 + wr * (BM / 2) + i * 16 + kg * 4;
      #pragma unroll
      for (int e = 0; e < 4; e++) {
        float v = acc[i][j][e] + bv;
        if (OUTMODE == 2) v = fmaxf(v, 0.0f);
        const size_t off = (size_t)(row0 + e) * N + col;
        if (OUTMODE == 3) outf[off] = v;
        else              outb[off] = bf16r(v);
      }
    }
  }
}

// ---------------------------------------------------------------------------
// Fused flash attention. Block = 256 threads (4 waves), grid = (B*H, S/128).
// Each wave owns 32 q rows (2 row-tiles). K-frags read from global (L2-hot),
// V^T staged in LDS (64KB, XOR swizzle). Swapped QK^T.
// ---------------------------------------------------------------------------
__launch_bounds__(256, 2)
__global__ void attn_kernel(const short* __restrict__ Qg, const short* __restrict__ Kg,
                            const short* __restrict__ Vg, const float* __restrict__ mask,
                            short* __restrict__ ctx) {
  __shared__ __align__(16) short Vt[64 * 512];   // [d][kv^swz], 64 KiB

  const int bh = blockIdx.x;            // 0..95
  const int b = bh / NH;
  const int h = bh % NH;
  const int tid  = threadIdx.x;
  const int lane = tid & 63;
  const int wid  = tid >> 6;
  const int l16  = lane & 15;
  const int kg   = lane >> 4;

  const short* Qb = Qg + (size_t)b * SEQ * DDIM + h * DHD;
  const short* Kb = Kg + (size_t)b * SEQ * DDIM + h * DHD;
  const short* Vb = Vg + (size_t)b * SEQ * DDIM + h * DHD;

  // stage V^T: Vt[d][kv ^ ((d&3)<<3)] = V[kv][d]
  for (int c = tid; c < SEQ * 8; c += 256) {
    const int kv = c >> 3;
    const int d0 = (c & 7) * 8;
    short8 v = *(const short8*)(Vb + (size_t)kv * DDIM + d0);
    #pragma unroll
    for (int j = 0; j < 8; j++)
      Vt[(d0 + j) * 512 + (kv ^ ((j & 3) << 3))] = v[j];
  }
  __syncthreads();

  const int q0 = blockIdx.y * 128 + wid * 32;

  // Q fragments (B operand: lane holds col q = l16, elems d = kg*8+j)
  short8 qf[2][2];
  #pragma unroll
  for (int rt = 0; rt < 2; rt++)
    #pragma unroll
    for (int dh = 0; dh < 2; dh++)
      qf[rt][dh] = *(const short8*)(Qb + (size_t)(q0 + rt * 16 + l16) * DDIM + dh * 32 + kg * 8);

  float mrun[2] = {-1e30f, -1e30f};
  float lrun[2] = {0.0f, 0.0f};
  const f32x4 zero = {0.f, 0.f, 0.f, 0.f};
  f32x4 oacc[2][4];
  #pragma unroll
  for (int rt = 0; rt < 2; rt++)
    #pragma unroll
    for (int dt = 0; dt < 4; dt++) oacc[rt][dt] = zero;

  const float* maskb = mask + (size_t)b * SEQ;

  for (int kv0 = 0; kv0 < SEQ; kv0 += 32) {
    // K fragments (A operand: lane holds row kv, elems d)
    short8 kf[2][2];
    #pragma unroll
    for (int kvh = 0; kvh < 2; kvh++)
      #pragma unroll
      for (int dh = 0; dh < 2; dh++)
        kf[kvh][dh] = *(const short8*)(Kb + (size_t)(kv0 + kvh * 16 + l16) * DDIM + dh * 32 + kg * 8);

    // V fragments (B operand of PV): lane holds col d = dt*16+l16, elems kv = kg*8+j
    short8 vf[4];
    #pragma unroll
    for (int dt = 0; dt < 4; dt++) {
      const int d = dt * 16 + l16;
      vf[dt] = *(const short8*)&Vt[d * 512 + ((kv0 + kg * 8) ^ ((d & 3) << 3))];
    }

    const f32x4 mq0 = *(const f32x4*)(maskb + kv0 + kg * 4);
    const f32x4 mq1 = *(const f32x4*)(maskb + kv0 + 16 + kg * 4);

    #pragma unroll
    for (int rt = 0; rt < 2; rt++) {
      f32x4 s0 = zero, s1 = zero;
      s0 = mfma_bf16(kf[0][0], qf[rt][0], s0);
      s0 = mfma_bf16(kf[0][1], qf[rt][1], s0);
      s1 = mfma_bf16(kf[1][0], qf[rt][0], s1);
      s1 = mfma_bf16(kf[1][1], qf[rt][1], s1);

      float p[8];
      #pragma unroll
      for (int e = 0; e < 4; e++) {
        p[e]     = s0[e] * 0.125f + mq0[e] * (-1e9f);
        p[e + 4] = s1[e] * 0.125f + mq1[e] * (-1e9f);
      }
      float mt = p[0];
      #pragma unroll
      for (int e = 1; e < 8; e++) mt = fmaxf(mt, p[e]);
      mt = fmaxf(mt, __shfl_xor(mt, 16, 64));
      mt = fmaxf(mt, __shfl_xor(mt, 32, 64));
      const float mnew = fmaxf(mrun[rt], mt);
      const float corr = __expf(mrun[rt] - mnew);
      float ts = 0.0f;
      #pragma unroll
      for (int e = 0; e < 8; e++) { p[e] = __expf(p[e] - mnew); ts += p[e]; }
      ts += __shfl_xor(ts, 16, 64);
      ts += __shfl_xor(ts, 32, 64);
      lrun[rt] = lrun[rt] * corr + ts;
      mrun[rt] = mnew;

      // pack p to bf16 pairs; redistribute to A-operand layout via shuffles
      const int P0 = (int)(((uint32_t)(uint16_t)bf16r(p[1]) << 16) | (uint16_t)bf16r(p[0]));
      const int P1 = (int)(((uint32_t)(uint16_t)bf16r(p[3]) << 16) | (uint16_t)bf16r(p[2]));
      const int P2 = (int)(((uint32_t)(uint16_t)bf16r(p[5]) << 16) | (uint16_t)bf16r(p[4]));
      const int P3 = (int)(((uint32_t)(uint16_t)bf16r(p[7]) << 16) | (uint16_t)bf16r(p[6]));
      const int sl0 = (((2 * kg) & 3) << 4) + l16;
      const int sl1 = (((2 * kg + 1) & 3) << 4) + l16;
      const int x0 = __shfl(P0, sl0, 64), y0 = __shfl(P2, sl0, 64);
      const int x1 = __shfl(P1, sl0, 64), y1 = __shfl(P3, sl0, 64);
      const int x2 = __shfl(P0, sl1, 64), y2 = __shfl(P2, sl1, 64);
      const int x3 = __shfl(P1, sl1, 64), y3 = __shfl(P3, sl1, 64);
      union { int w[4]; short8 v; } pa;
      const bool hi = (kg >= 2);
      pa.w[0] = hi ? y0 : x0;
      pa.w[1] = hi ? y1 : x1;
      pa.w[2] = hi ? y2 : x2;
      pa.w[3] = hi ? y3 : x3;

      // per-q-row rescale factors for O acc (O rows q = kg*4+e)
      const float c0 = __shfl(corr, kg * 4 + 0, 64);
      const float c1 = __shfl(corr, kg * 4 + 1, 64);
      const float c2 = __shfl(corr, kg * 4 + 2, 64);
      const float c3 = __shfl(corr, kg * 4 + 3, 64);

      #pragma unroll
      for (int dt = 0; dt < 4; dt++) {
        f32x4 o = oacc[rt][dt];
        o[0] *= c0; o[1] *= c1; o[2] *= c2; o[3] *= c3;
        oacc[rt][dt] = mfma_bf16(pa.v, vf[dt], o);
      }
    }
  }

  short* cb = ctx + (size_t)b * SEQ * DDIM + h * DHD;
  #pragma unroll
  for (int rt = 0; rt < 2; rt++) {
    const float li = 1.0f / lrun[rt];
    const float l0 = __shfl(li, kg * 4 + 0, 64);
    const float l1 = __shfl(li, kg * 4 + 1, 64);
    const float l2 = __shfl(li, kg * 4 + 2, 64);
    const float l3 = __shfl(li, kg * 4 + 3, 64);
    #pragma unroll
    for (int dt = 0; dt < 4; dt++) {
      const f32x4 o = oacc[rt][dt];
      const int col = dt * 16 + l16;
      const size_t base = (size_t)(q0 + rt * 16 + kg * 4) * DDIM + col;
      cb[base + 0 * DDIM] = bf16r(o[0] * l0);
      cb[base + 1 * DDIM] = bf16r(o[1] * l1);
      cb[base + 2 * DDIM] = bf16r(o[2] * l2);
      cb[base + 3 * DDIM] = bf16r(o[3] * l3);
    }
  }
}

// ---------------------------------------------------------------------------
// Fused split-K reduce + LayerNorm:
// y = LN(resid + p0 + p1 + pbias) -> fp32 out + bf16 out.
// One wave per row (768 = 12 elems/lane). In-place safe (reads before writes).
// ---------------------------------------------------------------------------
__launch_bounds__(256, 4)
__global__ void ln_red_kernel(const float* __restrict__ resid,
                              const float* __restrict__ p0,
                              const float* __restrict__ p1,
                              const float* __restrict__ pb,
                              const float* __restrict__ gw,
                              const float* __restrict__ bw,
                              float* __restrict__ outf, short* __restrict__ outb) {
  const int lane = threadIdx.x & 63;
  const int wid  = threadIdx.x >> 6;
  const int row  = blockIdx.x * 4 + wid;
  const size_t base = (size_t)row * DDIM;
  float v[12];
  float s = 0.0f;
  #pragma unroll
  for (int c = 0; c < 12; c++) {
    const int idx = c * 64 + lane;
    v[c] = resid[base + idx] + p0[base + idx] + p1[base + idx] + pb[idx];
    s += v[c];
  }
  #pragma unroll
  for (int o = 1; o < 64; o <<= 1) s += __shfl_xor(s, o, 64);
  const float mean = s * (1.0f / 768.0f);
  float q = 0.0f;
  #pragma unroll
  for (int c = 0; c < 12; c++) { const float d = v[c] - mean; q += d * d; }
  #pragma unroll
  for (int o = 1; o < 64; o <<= 1) q += __shfl_xor(q, o, 64);
  const float inv = 1.0f / sqrtf(q * (1.0f / 768.0f) + 1e-5f);
  #pragma unroll
  for (int c = 0; c < 12; c++) {
    const int idx = c * 64 + lane;
    const float y = gw[idx] * (v[c] - mean) * inv + bw[idx];
    outf[base + idx] = y;
    outb[base + idx] = bf16r(y);
  }
}

// ---------------------------------------------------------------------------
// Workspace (~79 MB):
//   H0   fp32 [4096][768]  residual stream (in-place LN)
//   Bbuf bf16 [4096][768]  bf16 of h / a
//   R1   bf16 [4096][3072] quarters: Q,K,V,ctx -> ffn1 full
//   WB   bf16 2*WFD        phase A: Wq,Wk,Wv,Wo ; phase B: W1,W2
//   P0,P1 fp32 [4096][768] split-K partial outputs (Oproj / FFN2)
// ---------------------------------------------------------------------------
extern "C" void kernel_launch(void* const* d_in, const int* in_sizes, int n_in,
                              void* d_out, int out_size, void* d_ws, size_t ws_size,
                              hipStream_t stream) {
  const float* x    = (const float*)d_in[0];
  const float* mask = (const float*)d_in[1];
  const float* Wq   = (const float*)d_in[2];
  const float* bq   = (const float*)d_in[3];
  const float* Wk   = (const float*)d_in[4];
  const float* bk   = (const float*)d_in[5];
  const float* Wv   = (const float*)d_in[6];
  const float* bv   = (const float*)d_in[7];
  const float* Wo   = (const float*)d_in[8];
  const float* bo   = (const float*)d_in[9];
  const float* g1   = (const float*)d_in[10];
  const float* b1   = (const float*)d_in[11];
  const float* W1   = (const float*)d_in[12];
  const float* bf1  = (const float*)d_in[13];
  const float* W2   = (const float*)d_in[14];
  const float* bf2  = (const float*)d_in[15];
  const float* g2   = (const float*)d_in[16];
  const float* b2   = (const float*)d_in[17];

  const size_t SD = (size_t)ROWS * DDIM;   // 3145728

  char* ws = (char*)d_ws;
  float* H0   = (float*)ws;  ws += SD * 4;                 // 12.58 MB
  short* Bbuf = (short*)ws;  ws += SD * 2;                 //  6.29 MB
  short* R1   = (short*)ws;  ws += (size_t)ROWS * DFF * 2; // 25.17 MB
  short* WB   = (short*)ws;  ws += (size_t)2 * WFD * 2;    //  9.44 MB
  float* P0   = (float*)ws;  ws += SD * 4;                 // 12.58 MB
  float* P1   = (float*)ws;                                // 12.58 MB

  short* Qb = R1;
  short* Kb = R1 + SD;
  short* Vb = R1 + 2 * SD;
  short* Cb = R1 + 3 * SD;

  // x -> bf16
  {
    WCvt c{};
    c.src[0] = x; c.dst[0] = Bbuf; c.n8[0] = (int)(SD / 8);
    wconv_kernel<<<dim3(1536, 1), 256, 0, stream>>>(c);
  }

  for (int l = 0; l < NLAYER; l++) {
    // phase A weights: Wq,Wk,Wv,Wo
    {
      WCvt c{};
      c.src[0] = Wq + (size_t)l * WDD; c.dst[0] = WB;           c.n8[0] = (int)(WDD / 8);
      c.src[1] = Wk + (size_t)l * WDD; c.dst[1] = WB + WDD;     c.n8[1] = (int)(WDD / 8);
      c.src[2] = Wv + (size_t)l * WDD; c.dst[2] = WB + 2 * WDD; c.n8[2] = (int)(WDD / 8);
      c.src[3] = Wo + (size_t)l * WDD; c.dst[3] = WB + 3 * WDD; c.n8[3] = (int)(WDD / 8);
      wconv_kernel<<<dim3(288, 4), 256, 0, stream>>>(c);
    }

    // QKV (fused via grid.z)
    {
      GemmB g{};
      g.W0 = WB;           g.b0 = bq + (size_t)l * DDIM; g.o0 = Qb;
      g.W1 = WB + WDD;     g.b1 = bk + (size_t)l * DDIM; g.o1 = Kb;
      g.W2 = WB + 2 * WDD; g.b2 = bv + (size_t)l * DDIM; g.o2 = Vb;
      gemm_bt<1, 128, 0><<<dim3(32, 6, 3), 256, 0, stream>>>(Bbuf, g, ROWS, DDIM, DDIM, DDIM);
    }

    // attention: ctx -> q3
    attn_kernel<<<dim3(NB * NH, 4), 256, 0, stream>>>(Qb, Kb, Vb, mask, Cb);

    // O projection, split-K2 -> P0,P1 (768 blocks = 3/CU)
    {
      GemmB g{};
      g.W0 = WB + 3 * WDD; g.b0 = bo; g.o0 = P0; g.o1 = P1;
      gemm_bt<3, 64, 1><<<dim3(64, 6, 2), 256, 0, stream>>>(Cb, g, ROWS, DDIM, DDIM, DDIM / 2);
    }

    // LN1 = reduce(P0+P1) + bias + LN(h + .) -> H0 (fp32) + Bbuf (bf16)
    ln_red_kernel<<<dim3(ROWS / 4), 256, 0, stream>>>(l ? H0 : x, P0, P1,
                                                      bo + (size_t)l * DDIM,
                                                      g1 + (size_t)l * DDIM, b1 + (size_t)l * DDIM,
                                                      H0, Bbuf);

    // phase B weights: W1,W2
    {
      WCvt c{};
      c.src[0] = W1 + (size_t)l * WFD; c.dst[0] = WB;       c.n8[0] = (int)(WFD / 8);
      c.src[1] = W2 + (size_t)l * WFD; c.dst[1] = WB + WFD; c.n8[1] = (int)(WFD / 8);
      wconv_kernel<<<dim3(1152, 2), 256, 0, stream>>>(c);
    }

    // FFN1 (bf16 + ReLU) -> R1 full
    {
      GemmB g{};
      g.W0 = WB; g.b0 = bf1 + (size_t)l * DFF; g.o0 = R1;
      gemm_bt<2, 128, 0><<<dim3(32, 24, 1), 256, 0, stream>>>(Bbuf, g, ROWS, DFF, DDIM, DDIM);
    }

    // FFN2, split-K2 -> P0,P1 (768 blocks, 48 steps each)
    {
      GemmB g{};
      g.W0 = WB + WFD; g.b0 = bf2; g.o0 = P0; g.o1 = P1;
      gemm_bt<3, 64, 1><<<dim3(64, 6, 2), 256, 0, stream>>>(R1, g, ROWS, DDIM, DFF, DFF / 2);
    }

    // LN2 = reduce(P0+P1) + bias + LN(a + .) -> H0 / d_out (fp32) + Bbuf (bf16)
    ln_red_kernel<<<dim3(ROWS / 4), 256, 0, stream>>>(H0, P0, P1,
                                                      bf2 + (size_t)l * DDIM,
                                                      g2 + (size_t)l * DDIM, b2 + (size_t)l * DDIM,
                                                      (l == NLAYER - 1) ? (float*)d_out : H0,
                                                      Bbuf);
  }
}

// Round 19
// 1954.584 us; speedup vs baseline: 1.0542x; 1.0072x over previous
//
#include <hip/hip_runtime.h>
#include <hip/hip_bf16.h>
#include <stdint.h>

#define DDIM 768
#define NH 12
#define DHD 64
#define DFF 3072
#define NLAYER 12
#define SEQ 512
#define NB 8
#define ROWS (NB*SEQ)   // 4096

typedef __attribute__((ext_vector_type(4))) float f32x4;
typedef __attribute__((ext_vector_type(8))) short short8;

#define S_BARRIER()  asm volatile("s_barrier" ::: "memory")
#define WAIT_LGKM0() asm volatile("s_waitcnt lgkmcnt(0)" ::: "memory")
#define WAIT_VM0()   asm volatile("s_waitcnt vmcnt(0)" ::: "memory")
#define WAIT_VM3()   asm volatile("s_waitcnt vmcnt(3)" ::: "memory")
#define WAIT_VM4()   asm volatile("s_waitcnt vmcnt(4)" ::: "memory")

#define WDD    589824          // 768*768
#define WFD    2359296         // 3072*768

static __device__ __forceinline__ short bf16r(float f) {
  union { float f; uint32_t u; } a; a.f = f;
  uint32_t u = a.u;
  u += 0x7FFFu + ((u >> 16) & 1u);   // RNE
  return (short)(u >> 16);
}

static __device__ __forceinline__ float bf2f(short s) {
  union { uint32_t u; float f; } c;
  c.u = ((uint32_t)(uint16_t)s) << 16;
  return c.f;
}

static __device__ __forceinline__ f32x4 mfma_bf16(short8 a, short8 b, f32x4 c) {
  return __builtin_amdgcn_mfma_f32_16x16x32_bf16(a, b, c, 0, 0, 0);
}

// async global->LDS, 16B per lane. LDS dest is wave-uniform base; HW scatters
// lane i to base + i*16B. Global src is per-lane.
static __device__ __forceinline__ void gload16(const void* g, void* l) {
  __builtin_amdgcn_global_load_lds(
      (__attribute__((address_space(1))) void*)(void*)(uintptr_t)g,
      (__attribute__((address_space(3))) void*)l,
      16, 0, 0);
}

static __device__ __forceinline__ void cvt8(const float* __restrict__ s,
                                            short* __restrict__ d) {
  f32x4 a = *(const f32x4*)(s);
  f32x4 b = *(const f32x4*)(s + 4);
  short8 o;
  o[0] = bf16r(a[0]); o[1] = bf16r(a[1]); o[2] = bf16r(a[2]); o[3] = bf16r(a[3]);
  o[4] = bf16r(b[0]); o[5] = bf16r(b[1]); o[6] = bf16r(b[2]); o[7] = bf16r(b[3]);
  *(short8*)d = o;
}

// ---------------------------------------------------------------------------
// x fp32 -> bf16 (preamble)
// ---------------------------------------------------------------------------
__global__ void xconv_kernel(const float* __restrict__ src, short* __restrict__ dst) {
  const int i = blockIdx.x * 256 + threadIdx.x;   // grid covers ROWS*DDIM/8
  cvt8(src + (size_t)i * 8, dst + (size_t)i * 8);
}

// ---------------------------------------------------------------------------
// Per-layer weight conversion, ALL SIX tensors in ONE launch: grid (1152, 6).
// y = {Wq,Wk,Wv,Wo,W1,W2}; y<4 guards to 288 blocks' worth of chunks.
// WB layout: Wq|Wk|Wv|Wo|W1|W2 (full layer resident -> no aliasing order).
// (R19: merges the former 2 serial launches; A-phase co-schedules with B.)
// ---------------------------------------------------------------------------
struct W6 {
  const float* src[6];   // layer-offset pointers
  short* wb;
};

__global__ void wconv6_kernel(W6 w) {
  const int y = blockIdx.y;
  const int n8 = (y < 4) ? (WDD / 8) : (WFD / 8);
  const int i = blockIdx.x * 256 + threadIdx.x;
  if (i >= n8) return;
  const int dstOff = (y < 4) ? y * WDD : 4 * WDD + (y - 4) * WFD;
  cvt8(w.src[y] + (size_t)i * 8, w.wb + dstOff + (size_t)i * 8);
}

// ---------------------------------------------------------------------------
// GEMM: C[M,N] = A[M,K] @ W[N,K]^T + bias   (bf16 in, fp32 acc)
// OUTMODE: 1 = bf16 out (+bias), 2 = bf16 out (+bias, ReLU),
//          3 = fp32 PARTIAL out (no bias; split-K half)
// BM x 128 tile, BK=32, 256 threads (4 waves, 2x2 wave grid).
// Counted-vmcnt pipeline (T4): depth-2 prefetch over 2 LDS buffers.
// SPLITK=1: blockIdx.z = K-half (Klen = K/2, Kstride = full K); partials to
// o0/o1 (3 blk/CU vs 1.5 -> R15's measured -131 us win).
// SPLITK=0: blockIdx.z selects (W, bias, out) triple (fused QKV).
// ---------------------------------------------------------------------------
struct GemmB {
  const short* W0; const short* W1; const short* W2;
  const float* b0; const float* b1; const float* b2;
  void* o0; void* o1; void* o2;
};

template<int OUTMODE, int BM, int SPLITK>
__launch_bounds__(256, 3)
__global__ void gemm_bt(const short* __restrict__ A, GemmB gb,
                        int M, int N, int Kstride, int Klen) {
  constexpr int MF  = BM / 32;   // row fragments per wave (4 or 2)
  constexpr int ISS = BM / 64;   // A staging issues per wave (2 or 1)

  const int z = blockIdx.z;
  const short* W;
  const float* bias;
  void* outp;
  if (SPLITK) {
    W    = gb.W0 + (size_t)z * Klen;       // column offset within each row
    bias = gb.b0;                          // unused (OUTMODE 3)
    outp = (z == 0) ? gb.o0 : gb.o1;
  } else {
    W    = (z == 0) ? gb.W0 : ((z == 1) ? gb.W1 : gb.W2);
    bias = (z == 0) ? gb.b0 : ((z == 1) ? gb.b1 : gb.b2);
    outp = (z == 0) ? gb.o0 : ((z == 1) ? gb.o1 : gb.o2);
  }

  __shared__ __align__(16) short As[2][BM * 32];
  __shared__ __align__(16) short Bs[2][128 * 32];

  const int tid  = threadIdx.x;
  const int lane = tid & 63;
  const int wid  = tid >> 6;
  const int l16  = lane & 15;
  const int kg   = lane >> 4;
  const int wr   = wid >> 1;
  const int wc   = wid & 1;
  const int m0   = blockIdx.x * BM;
  const int n0   = blockIdx.y * 128;

  const f32x4 zero = {0.f, 0.f, 0.f, 0.f};
  f32x4 acc[MF][4];
  #pragma unroll
  for (int i = 0; i < MF; i++)
    #pragma unroll
    for (int j = 0; j < 4; j++) acc[i][j] = zero;

  // staging: per issue, one wave covers 16 rows (64 lanes x 16B; 4 lanes/row)
  const int lrow = lane >> 2;          // 0..15
  const int lcol = (lane & 3) * 8;     // short offset within row
  const short* Ag = A + (size_t)(m0 + wid * (BM / 4) + lrow) * Kstride + lcol
                      + (SPLITK ? (size_t)z * Klen : 0);
  const short* Wg = W + (size_t)(n0 + wid * 32 + lrow) * Kstride + lcol;

  auto stage = [&](int buf, int k0) {
    #pragma unroll
    for (int j = 0; j < ISS; j++)
      gload16(Ag + k0 + (size_t)(j * 16) * Kstride, &As[buf][(wid * (BM / 4) + j * 16) * 32]);
    #pragma unroll
    for (int j = 0; j < 2; j++)
      gload16(Wg + k0 + (size_t)(j * 16) * Kstride, &Bs[buf][(wid * 32 + j * 16) * 32]);
  };

  const int nsteps = Klen >> 5;        // 12, 24, 48 or 96
  stage(0, 0);
  stage(1, 32);
  if (ISS == 2) { WAIT_VM4(); } else { WAIT_VM3(); }
  S_BARRIER();

  for (int t = 0; t < nsteps; ++t) {
    const int cur = t & 1;
    short8 af[MF], bfr[4];
    #pragma unroll
    for (int i = 0; i < MF; i++)
      af[i] = *(const short8*)&As[cur][(wr * (BM / 2) + i * 16 + l16) * 32 + kg * 8];
    #pragma unroll
    for (int j = 0; j < 4; j++)
      bfr[j] = *(const short8*)&Bs[cur][(wc * 64 + j * 16 + l16) * 32 + kg * 8];
    WAIT_LGKM0();                       // my reads of buf[cur] complete
    S_BARRIER();                        // all waves' reads complete -> reusable

    const bool pf = (t + 2 < nsteps);
    if (pf) stage(cur, (t + 2) << 5);   // overwrite consumed buffer
    __builtin_amdgcn_sched_barrier(0);  // MFMA stays after the stage issue
    #pragma unroll
    for (int i = 0; i < MF; i++)
      #pragma unroll
      for (int j = 0; j < 4; j++)
        acc[i][j] = mfma_bf16(af[i], bfr[j], acc[i][j]);
    __builtin_amdgcn_sched_barrier(0);  // MFMA stays before the vmcnt wait

    if (pf) { if (ISS == 2) { WAIT_VM4(); } else { WAIT_VM3(); } }
    else    { WAIT_VM0(); }             // tail: drain remaining loads
    S_BARRIER();                        // tile t+1 ready for all waves
  }

  float* outf = (float*)outp;
  short* outb = (short*)outp;
  #pragma unroll
  for (int j = 0; j < 4; j++) {
    const int col = n0 + wc * 64 + j * 16 + l16;
    const float bv = (OUTMODE == 3) ? 0.0f : bias[col];
    #pragma unroll
    for (int i = 0; i < MF; i++) {
      const int row0 = m0 + wr * (BM / 2) + i * 16 + kg * 4;
      #pragma unroll
      for (int e = 0; e < 4; e++) {
        float v = acc[i][j][e] + bv;
        if (OUTMODE == 2) v = fmaxf(v, 0.0f);
        const size_t off = (size_t)(row0 + e) * N + col;
        if (OUTMODE == 3) outf[off] = v;
        else              outb[off] = bf16r(v);
      }
    }
  }
}

// ---------------------------------------------------------------------------
// Fused flash attention. Block = 256 threads (4 waves), grid = (B*H, S/128).
// Each wave owns 32 q rows (2 row-tiles). K-frags read from global (L2-hot),
// V^T staged in LDS (64KB, XOR swizzle). Swapped QK^T.
// ---------------------------------------------------------------------------
__launch_bounds__(256, 2)
__global__ void attn_kernel(const short* __restrict__ Qg, const short* __restrict__ Kg,
                            const short* __restrict__ Vg, const float* __restrict__ mask,
                            short* __restrict__ ctx) {
  __shared__ __align__(16) short Vt[64 * 512];   // [d][kv^swz], 64 KiB

  const int bh = blockIdx.x;            // 0..95
  const int b = bh / NH;
  const int h = bh % NH;
  const int tid  = threadIdx.x;
  const int lane = tid & 63;
  const int wid  = tid >> 6;
  const int l16  = lane & 15;
  const int kg   = lane >> 4;

  const short* Qb = Qg + (size_t)b * SEQ * DDIM + h * DHD;
  const short* Kb = Kg + (size_t)b * SEQ * DDIM + h * DHD;
  const short* Vb = Vg + (size_t)b * SEQ * DDIM + h * DHD;

  // stage V^T: Vt[d][kv ^ ((d&3)<<3)] = V[kv][d]
  for (int c = tid; c < SEQ * 8; c += 256) {
    const int kv = c >> 3;
    const int d0 = (c & 7) * 8;
    short8 v = *(const short8*)(Vb + (size_t)kv * DDIM + d0);
    #pragma unroll
    for (int j = 0; j < 8; j++)
      Vt[(d0 + j) * 512 + (kv ^ ((j & 3) << 3))] = v[j];
  }
  __syncthreads();

  const int q0 = blockIdx.y * 128 + wid * 32;

  // Q fragments (B operand: lane holds col q = l16, elems d = kg*8+j)
  short8 qf[2][2];
  #pragma unroll
  for (int rt = 0; rt < 2; rt++)
    #pragma unroll
    for (int dh = 0; dh < 2; dh++)
      qf[rt][dh] = *(const short8*)(Qb + (size_t)(q0 + rt * 16 + l16) * DDIM + dh * 32 + kg * 8);

  float mrun[2] = {-1e30f, -1e30f};
  float lrun[2] = {0.0f, 0.0f};
  const f32x4 zero = {0.f, 0.f, 0.f, 0.f};
  f32x4 oacc[2][4];
  #pragma unroll
  for (int rt = 0; rt < 2; rt++)
    #pragma unroll
    for (int dt = 0; dt < 4; dt++) oacc[rt][dt] = zero;

  const float* maskb = mask + (size_t)b * SEQ;

  for (int kv0 = 0; kv0 < SEQ; kv0 += 32) {
    // K fragments (A operand: lane holds row kv, elems d)
    short8 kf[2][2];
    #pragma unroll
    for (int kvh = 0; kvh < 2; kvh++)
      #pragma unroll
      for (int dh = 0; dh < 2; dh++)
        kf[kvh][dh] = *(const short8*)(Kb + (size_t)(kv0 + kvh * 16 + l16) * DDIM + dh * 32 + kg * 8);

    // V fragments (B operand of PV): lane holds col d = dt*16+l16, elems kv = kg*8+j
    short8 vf[4];
    #pragma unroll
    for (int dt = 0; dt < 4; dt++) {
      const int d = dt * 16 + l16;
      vf[dt] = *(const short8*)&Vt[d * 512 + ((kv0 + kg * 8) ^ ((d & 3) << 3))];
    }

    const f32x4 mq0 = *(const f32x4*)(maskb + kv0 + kg * 4);
    const f32x4 mq1 = *(const f32x4*)(maskb + kv0 + 16 + kg * 4);

    #pragma unroll
    for (int rt = 0; rt < 2; rt++) {
      f32x4 s0 = zero, s1 = zero;
      s0 = mfma_bf16(kf[0][0], qf[rt][0], s0);
      s0 = mfma_bf16(kf[0][1], qf[rt][1], s0);
      s1 = mfma_bf16(kf[1][0], qf[rt][0], s1);
      s1 = mfma_bf16(kf[1][1], qf[rt][1], s1);

      float p[8];
      #pragma unroll
      for (int e = 0; e < 4; e++) {
        p[e]     = s0[e] * 0.125f + mq0[e] * (-1e9f);
        p[e + 4] = s1[e] * 0.125f + mq1[e] * (-1e9f);
      }
      float mt = p[0];
      #pragma unroll
      for (int e = 1; e < 8; e++) mt = fmaxf(mt, p[e]);
      mt = fmaxf(mt, __shfl_xor(mt, 16, 64));
      mt = fmaxf(mt, __shfl_xor(mt, 32, 64));
      const float mnew = fmaxf(mrun[rt], mt);
      const float corr = __expf(mrun[rt] - mnew);
      float ts = 0.0f;
      #pragma unroll
      for (int e = 0; e < 8; e++) { p[e] = __expf(p[e] - mnew); ts += p[e]; }
      ts += __shfl_xor(ts, 16, 64);
      ts += __shfl_xor(ts, 32, 64);
      lrun[rt] = lrun[rt] * corr + ts;
      mrun[rt] = mnew;

      // pack p to bf16 pairs; redistribute to A-operand layout via shuffles
      const int P0 = (int)(((uint32_t)(uint16_t)bf16r(p[1]) << 16) | (uint16_t)bf16r(p[0]));
      const int P1 = (int)(((uint32_t)(uint16_t)bf16r(p[3]) << 16) | (uint16_t)bf16r(p[2]));
      const int P2 = (int)(((uint32_t)(uint16_t)bf16r(p[5]) << 16) | (uint16_t)bf16r(p[4]));
      const int P3 = (int)(((uint32_t)(uint16_t)bf16r(p[7]) << 16) | (uint16_t)bf16r(p[6]));
      const int sl0 = (((2 * kg) & 3) << 4) + l16;
      const int sl1 = (((2 * kg + 1) & 3) << 4) + l16;
      const int x0 = __shfl(P0, sl0, 64), y0 = __shfl(P2, sl0, 64);
      const int x1 = __shfl(P1, sl0, 64), y1 = __shfl(P3, sl0, 64);
      const int x2 = __shfl(P0, sl1, 64), y2 = __shfl(P2, sl1, 64);
      const int x3 = __shfl(P1, sl1, 64), y3 = __shfl(P3, sl1, 64);
      union { int w[4]; short8 v; } pa;
      const bool hi = (kg >= 2);
      pa.w[0] = hi ? y0 : x0;
      pa.w[1] = hi ? y1 : x1;
      pa.w[2] = hi ? y2 : x2;
      pa.w[3] = hi ? y3 : x3;

      // per-q-row rescale factors for O acc (O rows q = kg*4+e)
      const float c0 = __shfl(corr, kg * 4 + 0, 64);
      const float c1 = __shfl(corr, kg * 4 + 1, 64);
      const float c2 = __shfl(corr, kg * 4 + 2, 64);
      const float c3 = __shfl(corr, kg * 4 + 3, 64);

      #pragma unroll
      for (int dt = 0; dt < 4; dt++) {
        f32x4 o = oacc[rt][dt];
        o[0] *= c0; o[1] *= c1; o[2] *= c2; o[3] *= c3;
        oacc[rt][dt] = mfma_bf16(pa.v, vf[dt], o);
      }
    }
  }

  short* cb = ctx + (size_t)b * SEQ * DDIM + h * DHD;
  #pragma unroll
  for (int rt = 0; rt < 2; rt++) {
    const float li = 1.0f / lrun[rt];
    const float l0 = __shfl(li, kg * 4 + 0, 64);
    const float l1 = __shfl(li, kg * 4 + 1, 64);
    const float l2 = __shfl(li, kg * 4 + 2, 64);
    const float l3 = __shfl(li, kg * 4 + 3, 64);
    #pragma unroll
    for (int dt = 0; dt < 4; dt++) {
      const f32x4 o = oacc[rt][dt];
      const int col = dt * 16 + l16;
      const size_t base = (size_t)(q0 + rt * 16 + kg * 4) * DDIM + col;
      cb[base + 0 * DDIM] = bf16r(o[0] * l0);
      cb[base + 1 * DDIM] = bf16r(o[1] * l1);
      cb[base + 2 * DDIM] = bf16r(o[2] * l2);
      cb[base + 3 * DDIM] = bf16r(o[3] * l3);
    }
  }
}

// ---------------------------------------------------------------------------
// Fused split-K reduce + LayerNorm:
// y = LN(resid + p0 + p1 + pbias) -> fp32 out + bf16 out.
// One wave per row (768 = 12 elems/lane). In-place safe (reads before writes).
// ---------------------------------------------------------------------------
__launch_bounds__(256, 4)
__global__ void ln_red_kernel(const float* __restrict__ resid,
                              const float* __restrict__ p0,
                              const float* __restrict__ p1,
                              const float* __restrict__ pb,
                              const float* __restrict__ gw,
                              const float* __restrict__ bw,
                              float* __restrict__ outf, short* __restrict__ outb) {
  const int lane = threadIdx.x & 63;
  const int wid  = threadIdx.x >> 6;
  const int row  = blockIdx.x * 4 + wid;
  const size_t base = (size_t)row * DDIM;
  float v[12];
  float s = 0.0f;
  #pragma unroll
  for (int c = 0; c < 12; c++) {
    const int idx = c * 64 + lane;
    v[c] = resid[base + idx] + p0[base + idx] + p1[base + idx] + pb[idx];
    s += v[c];
  }
  #pragma unroll
  for (int o = 1; o < 64; o <<= 1) s += __shfl_xor(s, o, 64);
  const float mean = s * (1.0f / 768.0f);
  float q = 0.0f;
  #pragma unroll
  for (int c = 0; c < 12; c++) { const float d = v[c] - mean; q += d * d; }
  #pragma unroll
  for (int o = 1; o < 64; o <<= 1) q += __shfl_xor(q, o, 64);
  const float inv = 1.0f / sqrtf(q * (1.0f / 768.0f) + 1e-5f);
  #pragma unroll
  for (int c = 0; c < 12; c++) {
    const int idx = c * 64 + lane;
    const float y = gw[idx] * (v[c] - mean) * inv + bw[idx];
    outf[base + idx] = y;
    outb[base + idx] = bf16r(y);
  }
}

// ---------------------------------------------------------------------------
// Workspace (~84 MB):
//   H0   fp32 [4096][768]  residual stream (in-place LN)
//   Bbuf bf16 [4096][768]  bf16 of h / a
//   R1   bf16 [4096][3072] quarters: Q,K,V,ctx -> ffn1 full
//   WB   bf16 WLAYER       full layer: Wq|Wk|Wv|Wo|W1|W2 (one wconv launch)
//   P0,P1 fp32 [4096][768] split-K partial outputs (Oproj / FFN2)
// ---------------------------------------------------------------------------
extern "C" void kernel_launch(void* const* d_in, const int* in_sizes, int n_in,
                              void* d_out, int out_size, void* d_ws, size_t ws_size,
                              hipStream_t stream) {
  const float* x    = (const float*)d_in[0];
  const float* mask = (const float*)d_in[1];
  const float* Wq   = (const float*)d_in[2];
  const float* bq   = (const float*)d_in[3];
  const float* Wk   = (const float*)d_in[4];
  const float* bk   = (const float*)d_in[5];
  const float* Wv   = (const float*)d_in[6];
  const float* bv   = (const float*)d_in[7];
  const float* Wo   = (const float*)d_in[8];
  const float* bo   = (const float*)d_in[9];
  const float* g1   = (const float*)d_in[10];
  const float* b1   = (const float*)d_in[11];
  const float* W1   = (const float*)d_in[12];
  const float* bf1  = (const float*)d_in[13];
  const float* W2   = (const float*)d_in[14];
  const float* bf2  = (const float*)d_in[15];
  const float* g2   = (const float*)d_in[16];
  const float* b2   = (const float*)d_in[17];

  const size_t SD = (size_t)ROWS * DDIM;   // 3145728

  char* ws = (char*)d_ws;
  float* H0   = (float*)ws;  ws += SD * 4;                       // 12.58 MB
  short* Bbuf = (short*)ws;  ws += SD * 2;                       //  6.29 MB
  short* R1   = (short*)ws;  ws += (size_t)ROWS * DFF * 2;       // 25.17 MB
  short* WB   = (short*)ws;  ws += (size_t)(4 * WDD + 2 * WFD) * 2; // 14.16 MB
  float* P0   = (float*)ws;  ws += SD * 4;                       // 12.58 MB
  float* P1   = (float*)ws;                                      // 12.58 MB

  short* Qb = R1;
  short* Kb = R1 + SD;
  short* Vb = R1 + 2 * SD;
  short* Cb = R1 + 3 * SD;

  // x -> bf16
  xconv_kernel<<<dim3((int)(SD / 8 / 256)), 256, 0, stream>>>(x, Bbuf);

  for (int l = 0; l < NLAYER; l++) {
    // all six weight tensors of layer l in ONE launch
    {
      W6 w{};
      w.src[0] = Wq + (size_t)l * WDD;
      w.src[1] = Wk + (size_t)l * WDD;
      w.src[2] = Wv + (size_t)l * WDD;
      w.src[3] = Wo + (size_t)l * WDD;
      w.src[4] = W1 + (size_t)l * WFD;
      w.src[5] = W2 + (size_t)l * WFD;
      w.wb = WB;
      wconv6_kernel<<<dim3(1152, 6), 256, 0, stream>>>(w);
    }

    // QKV (fused via grid.z)
    {
      GemmB g{};
      g.W0 = WB;           g.b0 = bq + (size_t)l * DDIM; g.o0 = Qb;
      g.W1 = WB + WDD;     g.b1 = bk + (size_t)l * DDIM; g.o1 = Kb;
      g.W2 = WB + 2 * WDD; g.b2 = bv + (size_t)l * DDIM; g.o2 = Vb;
      gemm_bt<1, 128, 0><<<dim3(32, 6, 3), 256, 0, stream>>>(Bbuf, g, ROWS, DDIM, DDIM, DDIM);
    }

    // attention: ctx -> q3
    attn_kernel<<<dim3(NB * NH, 4), 256, 0, stream>>>(Qb, Kb, Vb, mask, Cb);

    // O projection, split-K2 -> P0,P1 (768 blocks = 3/CU)
    {
      GemmB g{};
      g.W0 = WB + 3 * WDD; g.b0 = bo; g.o0 = P0; g.o1 = P1;
      gemm_bt<3, 64, 1><<<dim3(64, 6, 2), 256, 0, stream>>>(Cb, g, ROWS, DDIM, DDIM, DDIM / 2);
    }

    // LN1 = reduce(P0+P1) + bias + LN(h + .) -> H0 (fp32) + Bbuf (bf16)
    ln_red_kernel<<<dim3(ROWS / 4), 256, 0, stream>>>(l ? H0 : x, P0, P1,
                                                      bo + (size_t)l * DDIM,
                                                      g1 + (size_t)l * DDIM, b1 + (size_t)l * DDIM,
                                                      H0, Bbuf);

    // FFN1 (bf16 + ReLU) -> R1 full
    {
      GemmB g{};
      g.W0 = WB + 4 * WDD; g.b0 = bf1 + (size_t)l * DFF; g.o0 = R1;
      gemm_bt<2, 128, 0><<<dim3(32, 24, 1), 256, 0, stream>>>(Bbuf, g, ROWS, DFF, DDIM, DDIM);
    }

    // FFN2, split-K2 -> P0,P1 (768 blocks, 48 steps each)
    {
      GemmB g{};
      g.W0 = WB + 4 * WDD + WFD; g.b0 = bf2; g.o0 = P0; g.o1 = P1;
      gemm_bt<3, 64, 1><<<dim3(64, 6, 2), 256, 0, stream>>>(R1, g, ROWS, DDIM, DFF, DFF / 2);
    }

    // LN2 = reduce(P0+P1) + bias + LN(a + .) -> H0 / d_out (fp32) + Bbuf (bf16)
    ln_red_kernel<<<dim3(ROWS / 4), 256, 0, stream>>>(H0, P0, P1,
                                                      bf2 + (size_t)l * DDIM,
                                                      g2 + (size_t)l * DDIM, b2 + (size_t)l * DDIM,
                                                      (l == NLAYER - 1) ? (float*)d_out : H0,
                                                      Bbuf);
  }
}

// Round 21
// 1944.199 us; speedup vs baseline: 1.0598x; 1.0053x over previous
//
#include <hip/hip_runtime.h>
#include <hip/hip_bf16.h>
#include <stdint.h>

#define DDIM 768
#define NH 12
#define DHD 64
#define DFF 3072
#define NLAYER 12
#define SEQ 512
#define NB 8
#define ROWS (NB*SEQ)   // 4096

typedef __attribute__((ext_vector_type(4))) float f32x4;
typedef __attribute__((ext_vector_type(8))) short short8;
typedef __attribute__((ext_vector_type(4))) short s16x4;

#define S_BARRIER()  asm volatile("s_barrier" ::: "memory")
#define WAIT_LGKM0() asm volatile("s_waitcnt lgkmcnt(0)" ::: "memory")
#define WAIT_VM0()   asm volatile("s_waitcnt vmcnt(0)" ::: "memory")
#define WAIT_VM3()   asm volatile("s_waitcnt vmcnt(3)" ::: "memory")
#define WAIT_VM4()   asm volatile("s_waitcnt vmcnt(4)" ::: "memory")

#define WDD    589824          // 768*768
#define WFD    2359296         // 3072*768

static __device__ __forceinline__ short bf16r(float f) {
  union { float f; uint32_t u; } a; a.f = f;
  uint32_t u = a.u;
  u += 0x7FFFu + ((u >> 16) & 1u);   // RNE
  return (short)(u >> 16);
}

static __device__ __forceinline__ float bf2f(short s) {
  union { uint32_t u; float f; } c;
  c.u = ((uint32_t)(uint16_t)s) << 16;
  return c.f;
}

static __device__ __forceinline__ f32x4 mfma_bf16(short8 a, short8 b, f32x4 c) {
  return __builtin_amdgcn_mfma_f32_16x16x32_bf16(a, b, c, 0, 0, 0);
}

// async global->LDS, 16B per lane. LDS dest is wave-uniform base; HW scatters
// lane i to base + i*16B. Global src is per-lane.
static __device__ __forceinline__ void gload16(const void* g, void* l) {
  __builtin_amdgcn_global_load_lds(
      (__attribute__((address_space(1))) void*)(void*)(uintptr_t)g,
      (__attribute__((address_space(3))) void*)l,
      16, 0, 0);
}

static __device__ __forceinline__ void cvt8(const float* __restrict__ s,
                                            short* __restrict__ d) {
  f32x4 a = *(const f32x4*)(s);
  f32x4 b = *(const f32x4*)(s + 4);
  short8 o;
  o[0] = bf16r(a[0]); o[1] = bf16r(a[1]); o[2] = bf16r(a[2]); o[3] = bf16r(a[3]);
  o[4] = bf16r(b[0]); o[5] = bf16r(b[1]); o[6] = bf16r(b[2]); o[7] = bf16r(b[3]);
  *(short8*)d = o;
}

// ---------------------------------------------------------------------------
// x fp32 -> bf16 (preamble)
// ---------------------------------------------------------------------------
__global__ void xconv_kernel(const float* __restrict__ src, short* __restrict__ dst) {
  const int i = blockIdx.x * 256 + threadIdx.x;   // grid covers ROWS*DDIM/8
  cvt8(src + (size_t)i * 8, dst + (size_t)i * 8);
}

// ---------------------------------------------------------------------------
// Per-layer weight conversion, ALL SIX tensors in ONE launch: grid (1152, 6).
// y = {Wq,Wk,Wv,Wo,W1,W2}; y<4 guards to 288 blocks' worth of chunks.
// WB layout: Wq|Wk|Wv|Wo|W1|W2 (full layer resident -> no aliasing order).
// ---------------------------------------------------------------------------
struct W6 {
  const float* src[6];   // layer-offset pointers
  short* wb;
};

__global__ void wconv6_kernel(W6 w) {
  const int y = blockIdx.y;
  const int n8 = (y < 4) ? (WDD / 8) : (WFD / 8);
  const int i = blockIdx.x * 256 + threadIdx.x;
  if (i >= n8) return;
  const int dstOff = (y < 4) ? y * WDD : 4 * WDD + (y - 4) * WFD;
  cvt8(w.src[y] + (size_t)i * 8, w.wb + dstOff + (size_t)i * 8);
}

// ---------------------------------------------------------------------------
// GEMM: C[M,N] = A[M,K] @ W[N,K]^T + bias   (bf16 in, fp32 acc)
// OUTMODE: 1 = bf16 out (+bias), 2 = bf16 out (+bias, ReLU),
//          3 = fp32 PARTIAL out (no bias; split-K half)
// BM x 128 tile, BK=32, 256 threads (4 waves, 2x2 wave grid).
// Counted-vmcnt pipeline (T4): depth-2 prefetch over 2 LDS buffers.
// SPLITK=1: blockIdx.z = K-half; partials to o0/o1 (R15's -131 us win).
// SPLITK=0: blockIdx.z selects (W, bias, out) triple (fused QKV).
// ---------------------------------------------------------------------------
struct GemmB {
  const short* W0; const short* W1; const short* W2;
  const float* b0; const float* b1; const float* b2;
  void* o0; void* o1; void* o2;
};

template<int OUTMODE, int BM, int SPLITK>
__launch_bounds__(256, 3)
__global__ void gemm_bt(const short* __restrict__ A, GemmB gb,
                        int M, int N, int Kstride, int Klen) {
  constexpr int MF  = BM / 32;   // row fragments per wave (4 or 2)
  constexpr int ISS = BM / 64;   // A staging issues per wave (2 or 1)

  const int z = blockIdx.z;
  const short* W;
  const float* bias;
  void* outp;
  if (SPLITK) {
    W    = gb.W0 + (size_t)z * Klen;       // column offset within each row
    bias = gb.b0;                          // unused (OUTMODE 3)
    outp = (z == 0) ? gb.o0 : gb.o1;
  } else {
    W    = (z == 0) ? gb.W0 : ((z == 1) ? gb.W1 : gb.W2);
    bias = (z == 0) ? gb.b0 : ((z == 1) ? gb.b1 : gb.b2);
    outp = (z == 0) ? gb.o0 : ((z == 1) ? gb.o1 : gb.o2);
  }

  __shared__ __align__(16) short As[2][BM * 32];
  __shared__ __align__(16) short Bs[2][128 * 32];

  const int tid  = threadIdx.x;
  const int lane = tid & 63;
  const int wid  = tid >> 6;
  const int l16  = lane & 15;
  const int kg   = lane >> 4;
  const int wr   = wid >> 1;
  const int wc   = wid & 1;
  const int m0   = blockIdx.x * BM;
  const int n0   = blockIdx.y * 128;

  const f32x4 zero = {0.f, 0.f, 0.f, 0.f};
  f32x4 acc[MF][4];
  #pragma unroll
  for (int i = 0; i < MF; i++)
    #pragma unroll
    for (int j = 0; j < 4; j++) acc[i][j] = zero;

  // staging: per issue, one wave covers 16 rows (64 lanes x 16B; 4 lanes/row)
  const int lrow = lane >> 2;          // 0..15
  const int lcol = (lane & 3) * 8;     // short offset within row
  const short* Ag = A + (size_t)(m0 + wid * (BM / 4) + lrow) * Kstride + lcol
                      + (SPLITK ? (size_t)z * Klen : 0);
  const short* Wg = W + (size_t)(n0 + wid * 32 + lrow) * Kstride + lcol;

  auto stage = [&](int buf, int k0) {
    #pragma unroll
    for (int j = 0; j < ISS; j++)
      gload16(Ag + k0 + (size_t)(j * 16) * Kstride, &As[buf][(wid * (BM / 4) + j * 16) * 32]);
    #pragma unroll
    for (int j = 0; j < 2; j++)
      gload16(Wg + k0 + (size_t)(j * 16) * Kstride, &Bs[buf][(wid * 32 + j * 16) * 32]);
  };

  const int nsteps = Klen >> 5;        // 12, 24, 48 or 96
  stage(0, 0);
  stage(1, 32);
  if (ISS == 2) { WAIT_VM4(); } else { WAIT_VM3(); }
  S_BARRIER();

  for (int t = 0; t < nsteps; ++t) {
    const int cur = t & 1;
    short8 af[MF], bfr[4];
    #pragma unroll
    for (int i = 0; i < MF; i++)
      af[i] = *(const short8*)&As[cur][(wr * (BM / 2) + i * 16 + l16) * 32 + kg * 8];
    #pragma unroll
    for (int j = 0; j < 4; j++)
      bfr[j] = *(const short8*)&Bs[cur][(wc * 64 + j * 16 + l16) * 32 + kg * 8];
    WAIT_LGKM0();                       // my reads of buf[cur] complete
    S_BARRIER();                        // all waves' reads complete -> reusable

    const bool pf = (t + 2 < nsteps);
    if (pf) stage(cur, (t + 2) << 5);   // overwrite consumed buffer
    __builtin_amdgcn_sched_barrier(0);  // MFMA stays after the stage issue
    #pragma unroll
    for (int i = 0; i < MF; i++)
      #pragma unroll
      for (int j = 0; j < 4; j++)
        acc[i][j] = mfma_bf16(af[i], bfr[j], acc[i][j]);
    __builtin_amdgcn_sched_barrier(0);  // MFMA stays before the vmcnt wait

    if (pf) { if (ISS == 2) { WAIT_VM4(); } else { WAIT_VM3(); } }
    else    { WAIT_VM0(); }             // tail: drain remaining loads
    S_BARRIER();                        // tile t+1 ready for all waves
  }

  float* outf = (float*)outp;
  short* outb = (short*)outp;
  #pragma unroll
  for (int j = 0; j < 4; j++) {
    const int col = n0 + wc * 64 + j * 16 + l16;
    const float bv = (OUTMODE == 3) ? 0.0f : bias[col];
    #pragma unroll
    for (int i = 0; i < MF; i++) {
      const int row0 = m0 + wr * (BM / 2) + i * 16 + kg * 4;
      #pragma unroll
      for (int e = 0; e < 4; e++) {
        float v = acc[i][j][e] + bv;
        if (OUTMODE == 2) v = fmaxf(v, 0.0f);
        const size_t off = (size_t)(row0 + e) * N + col;
        if (OUTMODE == 3) outf[off] = v;
        else              outb[off] = bf16r(v);
      }
    }
  }
}

// ---------------------------------------------------------------------------
// Fused flash attention. Block = 256 threads (4 waves), grid = (B*H, S/128).
// Each wave owns 32 q rows (2 row-tiles). K-frags read from global (L2-hot),
// V^T staged in LDS (64KB, XOR swizzle). Swapped QK^T.
// ---------------------------------------------------------------------------
__launch_bounds__(256, 2)
__global__ void attn_kernel(const short* __restrict__ Qg, const short* __restrict__ Kg,
                            const short* __restrict__ Vg, const float* __restrict__ mask,
                            short* __restrict__ ctx) {
  __shared__ __align__(16) short Vt[64 * 512];   // [d][kv^swz], 64 KiB

  const int bh = blockIdx.x;            // 0..95
  const int b = bh / NH;
  const int h = bh % NH;
  const int tid  = threadIdx.x;
  const int lane = tid & 63;
  const int wid  = tid >> 6;
  const int l16  = lane & 15;
  const int kg   = lane >> 4;

  const short* Qb = Qg + (size_t)b * SEQ * DDIM + h * DHD;
  const short* Kb = Kg + (size_t)b * SEQ * DDIM + h * DHD;
  const short* Vb = Vg + (size_t)b * SEQ * DDIM + h * DHD;

  // stage V^T: Vt[d][kv ^ ((d&3)<<3)] = V[kv][d]
  for (int c = tid; c < SEQ * 8; c += 256) {
    const int kv = c >> 3;
    const int d0 = (c & 7) * 8;
    short8 v = *(const short8*)(Vb + (size_t)kv * DDIM + d0);
    #pragma unroll
    for (int j = 0; j < 8; j++)
      Vt[(d0 + j) * 512 + (kv ^ ((j & 3) << 3))] = v[j];
  }
  __syncthreads();

  const int q0 = blockIdx.y * 128 + wid * 32;

  // Q fragments (B operand: lane holds col q = l16, elems d = kg*8+j)
  short8 qf[2][2];
  #pragma unroll
  for (int rt = 0; rt < 2; rt++)
    #pragma unroll
    for (int dh = 0; dh < 2; dh++)
      qf[rt][dh] = *(const short8*)(Qb + (size_t)(q0 + rt * 16 + l16) * DDIM + dh * 32 + kg * 8);

  float mrun[2] = {-1e30f, -1e30f};
  float lrun[2] = {0.0f, 0.0f};
  const f32x4 zero = {0.f, 0.f, 0.f, 0.f};
  f32x4 oacc[2][4];
  #pragma unroll
  for (int rt = 0; rt < 2; rt++)
    #pragma unroll
    for (int dt = 0; dt < 4; dt++) oacc[rt][dt] = zero;

  const float* maskb = mask + (size_t)b * SEQ;

  for (int kv0 = 0; kv0 < SEQ; kv0 += 32) {
    // K fragments (A operand: lane holds row kv, elems d)
    short8 kf[2][2];
    #pragma unroll
    for (int kvh = 0; kvh < 2; kvh++)
      #pragma unroll
      for (int dh = 0; dh < 2; dh++)
        kf[kvh][dh] = *(const short8*)(Kb + (size_t)(kv0 + kvh * 16 + l16) * DDIM + dh * 32 + kg * 8);

    // V fragments (B operand of PV): lane holds col d = dt*16+l16, elems kv = kg*8+j
    short8 vf[4];
    #pragma unroll
    for (int dt = 0; dt < 4; dt++) {
      const int d = dt * 16 + l16;
      vf[dt] = *(const short8*)&Vt[d * 512 + ((kv0 + kg * 8) ^ ((d & 3) << 3))];
    }

    const f32x4 mq0 = *(const f32x4*)(maskb + kv0 + kg * 4);
    const f32x4 mq1 = *(const f32x4*)(maskb + kv0 + 16 + kg * 4);

    #pragma unroll
    for (int rt = 0; rt < 2; rt++) {
      f32x4 s0 = zero, s1 = zero;
      s0 = mfma_bf16(kf[0][0], qf[rt][0], s0);
      s0 = mfma_bf16(kf[0][1], qf[rt][1], s0);
      s1 = mfma_bf16(kf[1][0], qf[rt][0], s1);
      s1 = mfma_bf16(kf[1][1], qf[rt][1], s1);

      float p[8];
      #pragma unroll
      for (int e = 0; e < 4; e++) {
        p[e]     = s0[e] * 0.125f + mq0[e] * (-1e9f);
        p[e + 4] = s1[e] * 0.125f + mq1[e] * (-1e9f);
      }
      float mt = p[0];
      #pragma unroll
      for (int e = 1; e < 8; e++) mt = fmaxf(mt, p[e]);
      mt = fmaxf(mt, __shfl_xor(mt, 16, 64));
      mt = fmaxf(mt, __shfl_xor(mt, 32, 64));
      const float mnew = fmaxf(mrun[rt], mt);
      const float corr = __expf(mrun[rt] - mnew);
      float ts = 0.0f;
      #pragma unroll
      for (int e = 0; e < 8; e++) { p[e] = __expf(p[e] - mnew); ts += p[e]; }
      ts += __shfl_xor(ts, 16, 64);
      ts += __shfl_xor(ts, 32, 64);
      lrun[rt] = lrun[rt] * corr + ts;
      mrun[rt] = mnew;

      // pack p to bf16 pairs; redistribute to A-operand layout via shuffles
      const int P0 = (int)(((uint32_t)(uint16_t)bf16r(p[1]) << 16) | (uint16_t)bf16r(p[0]));
      const int P1 = (int)(((uint32_t)(uint16_t)bf16r(p[3]) << 16) | (uint16_t)bf16r(p[2]));
      const int P2 = (int)(((uint32_t)(uint16_t)bf16r(p[5]) << 16) | (uint16_t)bf16r(p[4]));
      const int P3 = (int)(((uint32_t)(uint16_t)bf16r(p[7]) << 16) | (uint16_t)bf16r(p[6]));
      const int sl0 = (((2 * kg) & 3) << 4) + l16;
      const int sl1 = (((2 * kg + 1) & 3) << 4) + l16;
      const int x0 = __shfl(P0, sl0, 64), y0 = __shfl(P2, sl0, 64);
      const int x1 = __shfl(P1, sl0, 64), y1 = __shfl(P3, sl0, 64);
      const int x2 = __shfl(P0, sl1, 64), y2 = __shfl(P2, sl1, 64);
      const int x3 = __shfl(P1, sl1, 64), y3 = __shfl(P3, sl1, 64);
      union { int w[4]; short8 v; } pa;
      const bool hi = (kg >= 2);
      pa.w[0] = hi ? y0 : x0;
      pa.w[1] = hi ? y1 : x1;
      pa.w[2] = hi ? y2 : x2;
      pa.w[3] = hi ? y3 : x3;

      // per-q-row rescale factors for O acc (O rows q = kg*4+e)
      const float c0 = __shfl(corr, kg * 4 + 0, 64);
      const float c1 = __shfl(corr, kg * 4 + 1, 64);
      const float c2 = __shfl(corr, kg * 4 + 2, 64);
      const float c3 = __shfl(corr, kg * 4 + 3, 64);

      #pragma unroll
      for (int dt = 0; dt < 4; dt++) {
        f32x4 o = oacc[rt][dt];
        o[0] *= c0; o[1] *= c1; o[2] *= c2; o[3] *= c3;
        oacc[rt][dt] = mfma_bf16(pa.v, vf[dt], o);
      }
    }
  }

  short* cb = ctx + (size_t)b * SEQ * DDIM + h * DHD;
  #pragma unroll
  for (int rt = 0; rt < 2; rt++) {
    const float li = 1.0f / lrun[rt];
    const float l0 = __shfl(li, kg * 4 + 0, 64);
    const float l1 = __shfl(li, kg * 4 + 1, 64);
    const float l2 = __shfl(li, kg * 4 + 2, 64);
    const float l3 = __shfl(li, kg * 4 + 3, 64);
    #pragma unroll
    for (int dt = 0; dt < 4; dt++) {
      const f32x4 o = oacc[rt][dt];
      const int col = dt * 16 + l16;
      const size_t base = (size_t)(q0 + rt * 16 + kg * 4) * DDIM + col;
      cb[base + 0 * DDIM] = bf16r(o[0] * l0);
      cb[base + 1 * DDIM] = bf16r(o[1] * l1);
      cb[base + 2 * DDIM] = bf16r(o[2] * l2);
      cb[base + 3 * DDIM] = bf16r(o[3] * l3);
    }
  }
}

// ---------------------------------------------------------------------------
// Fused split-K reduce + LayerNorm, float4-vectorized (R20/R21, G13):
// y = LN(resid + p0 + p1 + pbias) -> fp32 out + bf16 out.
// One wave per row; lane i covers cols {c*256 + i*4 .. +3}, c = 0..2:
// 9 dwordx4 loads (resid,p0,p1) + 3 (g) + 3 (b); bf16 out as 8-B packed.
// In-place safe (all reads into v[12] before any write).
// ---------------------------------------------------------------------------
__launch_bounds__(256, 4)
__global__ void ln_red_kernel(const float* __restrict__ resid,
                              const float* __restrict__ p0,
                              const float* __restrict__ p1,
                              const float* __restrict__ pb,
                              const float* __restrict__ gw,
                              const float* __restrict__ bw,
                              float* __restrict__ outf, short* __restrict__ outb) {
  const int lane = threadIdx.x & 63;
  const int wid  = threadIdx.x >> 6;
  const int row  = blockIdx.x * 4 + wid;
  const size_t base = (size_t)row * DDIM;
  float v[12];
  float s = 0.0f;
  #pragma unroll
  for (int c = 0; c < 3; c++) {
    const int col = c * 256 + lane * 4;
    const f32x4 r  = *(const f32x4*)(resid + base + col);
    const f32x4 q0 = *(const f32x4*)(p0 + base + col);
    const f32x4 q1 = *(const f32x4*)(p1 + base + col);
    const f32x4 bb = *(const f32x4*)(pb + col);
    #pragma unroll
    for (int j = 0; j < 4; j++) {
      const float a = r[j] + q0[j] + q1[j] + bb[j];
      v[c * 4 + j] = a;
      s += a;
    }
  }
  #pragma unroll
  for (int o = 1; o < 64; o <<= 1) s += __shfl_xor(s, o, 64);
  const float mean = s * (1.0f / 768.0f);
  float q = 0.0f;
  #pragma unroll
  for (int c = 0; c < 12; c++) { const float d = v[c] - mean; q += d * d; }
  #pragma unroll
  for (int o = 1; o < 64; o <<= 1) q += __shfl_xor(q, o, 64);
  const float inv = 1.0f / sqrtf(q * (1.0f / 768.0f) + 1e-5f);
  #pragma unroll
  for (int c = 0; c < 3; c++) {
    const int col = c * 256 + lane * 4;
    const f32x4 g4 = *(const f32x4*)(gw + col);
    const f32x4 b4 = *(const f32x4*)(bw + col);
    f32x4 y4;
    s16x4 o4;
    #pragma unroll
    for (int j = 0; j < 4; j++) {
      const float y = g4[j] * (v[c * 4 + j] - mean) * inv + b4[j];
      y4[j] = y;
      o4[j] = bf16r(y);
    }
    *(f32x4*)(outf + base + col) = y4;
    *(s16x4*)(outb + base + col) = o4;
  }
}

// ---------------------------------------------------------------------------
// Workspace (~84 MB):
//   H0   fp32 [4096][768]  residual stream (in-place LN)
//   Bbuf bf16 [4096][768]  bf16 of h / a
//   R1   bf16 [4096][3072] quarters: Q,K,V,ctx -> ffn1 full
//   WB   bf16 WLAYER       full layer: Wq|Wk|Wv|Wo|W1|W2 (one wconv launch)
//   P0,P1 fp32 [4096][768] split-K partial outputs (Oproj / FFN2)
// ---------------------------------------------------------------------------
extern "C" void kernel_launch(void* const* d_in, const int* in_sizes, int n_in,
                              void* d_out, int out_size, void* d_ws, size_t ws_size,
                              hipStream_t stream) {
  const float* x    = (const float*)d_in[0];
  const float* mask = (const float*)d_in[1];
  const float* Wq   = (const float*)d_in[2];
  const float* bq   = (const float*)d_in[3];
  const float* Wk   = (const float*)d_in[4];
  const float* bk   = (const float*)d_in[5];
  const float* Wv   = (const float*)d_in[6];
  const float* bv   = (const float*)d_in[7];
  const float* Wo   = (const float*)d_in[8];
  const float* bo   = (const float*)d_in[9];
  const float* g1   = (const float*)d_in[10];
  const float* b1   = (const float*)d_in[11];
  const float* W1   = (const float*)d_in[12];
  const float* bf1  = (const float*)d_in[13];
  const float* W2   = (const float*)d_in[14];
  const float* bf2  = (const float*)d_in[15];
  const float* g2   = (const float*)d_in[16];
  const float* b2   = (const float*)d_in[17];

  const size_t SD = (size_t)ROWS * DDIM;   // 3145728

  char* ws = (char*)d_ws;
  float* H0   = (float*)ws;  ws += SD * 4;                       // 12.58 MB
  short* Bbuf = (short*)ws;  ws += SD * 2;                       //  6.29 MB
  short* R1   = (short*)ws;  ws += (size_t)ROWS * DFF * 2;       // 25.17 MB
  short* WB   = (short*)ws;  ws += (size_t)(4 * WDD + 2 * WFD) * 2; // 14.16 MB
  float* P0   = (float*)ws;  ws += SD * 4;                       // 12.58 MB
  float* P1   = (float*)ws;                                      // 12.58 MB

  short* Qb = R1;
  short* Kb = R1 + SD;
  short* Vb = R1 + 2 * SD;
  short* Cb = R1 + 3 * SD;

  // x -> bf16
  xconv_kernel<<<dim3((int)(SD / 8 / 256)), 256, 0, stream>>>(x, Bbuf);

  for (int l = 0; l < NLAYER; l++) {
    // all six weight tensors of layer l in ONE launch
    {
      W6 w{};
      w.src[0] = Wq + (size_t)l * WDD;
      w.src[1] = Wk + (size_t)l * WDD;
      w.src[2] = Wv + (size_t)l * WDD;
      w.src[3] = Wo + (size_t)l * WDD;
      w.src[4] = W1 + (size_t)l * WFD;
      w.src[5] = W2 + (size_t)l * WFD;
      w.wb = WB;
      wconv6_kernel<<<dim3(1152, 6), 256, 0, stream>>>(w);
    }

    // QKV (fused via grid.z)
    {
      GemmB g{};
      g.W0 = WB;           g.b0 = bq + (size_t)l * DDIM; g.o0 = Qb;
      g.W1 = WB + WDD;     g.b1 = bk + (size_t)l * DDIM; g.o1 = Kb;
      g.W2 = WB + 2 * WDD; g.b2 = bv + (size_t)l * DDIM; g.o2 = Vb;
      gemm_bt<1, 128, 0><<<dim3(32, 6, 3), 256, 0, stream>>>(Bbuf, g, ROWS, DDIM, DDIM, DDIM);
    }

    // attention: ctx -> q3
    attn_kernel<<<dim3(NB * NH, 4), 256, 0, stream>>>(Qb, Kb, Vb, mask, Cb);

    // O projection, split-K2 -> P0,P1 (768 blocks = 3/CU)
    {
      GemmB g{};
      g.W0 = WB + 3 * WDD; g.b0 = bo; g.o0 = P0; g.o1 = P1;
      gemm_bt<3, 64, 1><<<dim3(64, 6, 2), 256, 0, stream>>>(Cb, g, ROWS, DDIM, DDIM, DDIM / 2);
    }

    // LN1 = reduce(P0+P1) + bias + LN(h + .) -> H0 (fp32) + Bbuf (bf16)
    ln_red_kernel<<<dim3(ROWS / 4), 256, 0, stream>>>(l ? H0 : x, P0, P1,
                                                      bo + (size_t)l * DDIM,
                                                      g1 + (size_t)l * DDIM, b1 + (size_t)l * DDIM,
                                                      H0, Bbuf);

    // FFN1 (bf16 + ReLU) -> R1 full
    {
      GemmB g{};
      g.W0 = WB + 4 * WDD; g.b0 = bf1 + (size_t)l * DFF; g.o0 = R1;
      gemm_bt<2, 128, 0><<<dim3(32, 24, 1), 256, 0, stream>>>(Bbuf, g, ROWS, DFF, DDIM, DDIM);
    }

    // FFN2, split-K2 -> P0,P1 (768 blocks, 48 steps each)
    {
      GemmB g{};
      g.W0 = WB + 4 * WDD + WFD; g.b0 = bf2; g.o0 = P0; g.o1 = P1;
      gemm_bt<3, 64, 1><<<dim3(64, 6, 2), 256, 0, stream>>>(R1, g, ROWS, DDIM, DFF, DFF / 2);
    }

    // LN2 = reduce(P0+P1) + bias + LN(a + .) -> H0 / d_out (fp32) + Bbuf (bf16)
    ln_red_kernel<<<dim3(ROWS / 4), 256, 0, stream>>>(H0, P0, P1,
                                                      bf2 + (size_t)l * DDIM,
                                                      g2 + (size_t)l * DDIM, b2 + (size_t)l * DDIM,
                                                      (l == NLAYER - 1) ? (float*)d_out : H0,
                                                      Bbuf);
  }
}

// Round 22
// 1934.259 us; speedup vs baseline: 1.0653x; 1.0051x over previous
//
#include <hip/hip_runtime.h>
#include <hip/hip_bf16.h>
#include <stdint.h>

#define DDIM 768
#define NH 12
#define DHD 64
#define DFF 3072
#define NLAYER 12
#define SEQ 512
#define NB 8
#define ROWS (NB*SEQ)   // 4096

typedef __attribute__((ext_vector_type(4))) float f32x4;
typedef __attribute__((ext_vector_type(8))) short short8;
typedef __attribute__((ext_vector_type(4))) short s16x4;

#define S_BARRIER()  asm volatile("s_barrier" ::: "memory")
#define WAIT_LGKM0() asm volatile("s_waitcnt lgkmcnt(0)" ::: "memory")
#define WAIT_VM0()   asm volatile("s_waitcnt vmcnt(0)" ::: "memory")
#define WAIT_VM3()   asm volatile("s_waitcnt vmcnt(3)" ::: "memory")
#define WAIT_VM4()   asm volatile("s_waitcnt vmcnt(4)" ::: "memory")

#define WDD    589824          // 768*768
#define WFD    2359296         // 3072*768

static __device__ __forceinline__ short bf16r(float f) {
  union { float f; uint32_t u; } a; a.f = f;
  uint32_t u = a.u;
  u += 0x7FFFu + ((u >> 16) & 1u);   // RNE
  return (short)(u >> 16);
}

static __device__ __forceinline__ float bf2f(short s) {
  union { uint32_t u; float f; } c;
  c.u = ((uint32_t)(uint16_t)s) << 16;
  return c.f;
}

static __device__ __forceinline__ f32x4 mfma_bf16(short8 a, short8 b, f32x4 c) {
  return __builtin_amdgcn_mfma_f32_16x16x32_bf16(a, b, c, 0, 0, 0);
}

// async global->LDS, 16B per lane. LDS dest is wave-uniform base; HW scatters
// lane i to base + i*16B. Global src is per-lane.
static __device__ __forceinline__ void gload16(const void* g, void* l) {
  __builtin_amdgcn_global_load_lds(
      (__attribute__((address_space(1))) void*)(void*)(uintptr_t)g,
      (__attribute__((address_space(3))) void*)l,
      16, 0, 0);
}

static __device__ __forceinline__ void cvt8(const float* __restrict__ s,
                                            short* __restrict__ d) {
  f32x4 a = *(const f32x4*)(s);
  f32x4 b = *(const f32x4*)(s + 4);
  short8 o;
  o[0] = bf16r(a[0]); o[1] = bf16r(a[1]); o[2] = bf16r(a[2]); o[3] = bf16r(a[3]);
  o[4] = bf16r(b[0]); o[5] = bf16r(b[1]); o[6] = bf16r(b[2]); o[7] = bf16r(b[3]);
  *(short8*)d = o;
}

// ---------------------------------------------------------------------------
// x fp32 -> bf16 (preamble)
// ---------------------------------------------------------------------------
__global__ void xconv_kernel(const float* __restrict__ src, short* __restrict__ dst) {
  const int i = blockIdx.x * 256 + threadIdx.x;   // grid covers ROWS*DDIM/8
  cvt8(src + (size_t)i * 8, dst + (size_t)i * 8);
}

// ---------------------------------------------------------------------------
// Per-layer weight conversion, ALL SIX tensors in ONE launch: grid (1152, 6).
// y = {Wq,Wk,Wv,Wo,W1,W2}; y<4 guards to 288 blocks' worth of chunks.
// WB layout: Wq|Wk|Wv|Wo|W1|W2 (full layer resident -> no aliasing order).
// ---------------------------------------------------------------------------
struct W6 {
  const float* src[6];   // layer-offset pointers
  short* wb;
};

__global__ void wconv6_kernel(W6 w) {
  const int y = blockIdx.y;
  const int n8 = (y < 4) ? (WDD / 8) : (WFD / 8);
  const int i = blockIdx.x * 256 + threadIdx.x;
  if (i >= n8) return;
  const int dstOff = (y < 4) ? y * WDD : 4 * WDD + (y - 4) * WFD;
  cvt8(w.src[y] + (size_t)i * 8, w.wb + dstOff + (size_t)i * 8);
}

// ---------------------------------------------------------------------------
// GEMM: C[M,N] = A[M,K] @ W[N,K]^T + bias   (bf16 in, fp32 acc)
// OUTMODE: 1 = bf16 out (+bias), 2 = bf16 out (+bias, ReLU),
//          3 = fp32 PARTIAL out (no bias; split-K half)
// BM x 128 tile, BK=32, 256 threads (4 waves, 2x2 wave grid).
// Counted-vmcnt pipeline (T4): depth-2 prefetch over 2 LDS buffers.
// SPLITK=1: blockIdx.z = K-half; partials to o0/o1 (R15's -131 us win).
// SPLITK=0: blockIdx.z selects (W, bias, out) triple (fused QKV).
// ---------------------------------------------------------------------------
struct GemmB {
  const short* W0; const short* W1; const short* W2;
  const float* b0; const float* b1; const float* b2;
  void* o0; void* o1; void* o2;
};

template<int OUTMODE, int BM, int SPLITK>
__launch_bounds__(256, 3)
__global__ void gemm_bt(const short* __restrict__ A, GemmB gb,
                        int M, int N, int Kstride, int Klen) {
  constexpr int MF  = BM / 32;   // row fragments per wave (4 or 2)
  constexpr int ISS = BM / 64;   // A staging issues per wave (2 or 1)

  const int z = blockIdx.z;
  const short* W;
  const float* bias;
  void* outp;
  if (SPLITK) {
    W    = gb.W0 + (size_t)z * Klen;       // column offset within each row
    bias = gb.b0;                          // unused (OUTMODE 3)
    outp = (z == 0) ? gb.o0 : gb.o1;
  } else {
    W    = (z == 0) ? gb.W0 : ((z == 1) ? gb.W1 : gb.W2);
    bias = (z == 0) ? gb.b0 : ((z == 1) ? gb.b1 : gb.b2);
    outp = (z == 0) ? gb.o0 : ((z == 1) ? gb.o1 : gb.o2);
  }

  __shared__ __align__(16) short As[2][BM * 32];
  __shared__ __align__(16) short Bs[2][128 * 32];

  const int tid  = threadIdx.x;
  const int lane = tid & 63;
  const int wid  = tid >> 6;
  const int l16  = lane & 15;
  const int kg   = lane >> 4;
  const int wr   = wid >> 1;
  const int wc   = wid & 1;
  const int m0   = blockIdx.x * BM;
  const int n0   = blockIdx.y * 128;

  const f32x4 zero = {0.f, 0.f, 0.f, 0.f};
  f32x4 acc[MF][4];
  #pragma unroll
  for (int i = 0; i < MF; i++)
    #pragma unroll
    for (int j = 0; j < 4; j++) acc[i][j] = zero;

  // staging: per issue, one wave covers 16 rows (64 lanes x 16B; 4 lanes/row)
  const int lrow = lane >> 2;          // 0..15
  const int lcol = (lane & 3) * 8;     // short offset within row
  const short* Ag = A + (size_t)(m0 + wid * (BM / 4) + lrow) * Kstride + lcol
                      + (SPLITK ? (size_t)z * Klen : 0);
  const short* Wg = W + (size_t)(n0 + wid * 32 + lrow) * Kstride + lcol;

  auto stage = [&](int buf, int k0) {
    #pragma unroll
    for (int j = 0; j < ISS; j++)
      gload16(Ag + k0 + (size_t)(j * 16) * Kstride, &As[buf][(wid * (BM / 4) + j * 16) * 32]);
    #pragma unroll
    for (int j = 0; j < 2; j++)
      gload16(Wg + k0 + (size_t)(j * 16) * Kstride, &Bs[buf][(wid * 32 + j * 16) * 32]);
  };

  const int nsteps = Klen >> 5;        // 12, 24, 48 or 96
  stage(0, 0);
  stage(1, 32);
  if (ISS == 2) { WAIT_VM4(); } else { WAIT_VM3(); }
  S_BARRIER();

  for (int t = 0; t < nsteps; ++t) {
    const int cur = t & 1;
    short8 af[MF], bfr[4];
    #pragma unroll
    for (int i = 0; i < MF; i++)
      af[i] = *(const short8*)&As[cur][(wr * (BM / 2) + i * 16 + l16) * 32 + kg * 8];
    #pragma unroll
    for (int j = 0; j < 4; j++)
      bfr[j] = *(const short8*)&Bs[cur][(wc * 64 + j * 16 + l16) * 32 + kg * 8];
    WAIT_LGKM0();                       // my reads of buf[cur] complete
    S_BARRIER();                        // all waves' reads complete -> reusable

    const bool pf = (t + 2 < nsteps);
    if (pf) stage(cur, (t + 2) << 5);   // overwrite consumed buffer
    __builtin_amdgcn_sched_barrier(0);  // MFMA stays after the stage issue
    #pragma unroll
    for (int i = 0; i < MF; i++)
      #pragma unroll
      for (int j = 0; j < 4; j++)
        acc[i][j] = mfma_bf16(af[i], bfr[j], acc[i][j]);
    __builtin_amdgcn_sched_barrier(0);  // MFMA stays before the vmcnt wait

    if (pf) { if (ISS == 2) { WAIT_VM4(); } else { WAIT_VM3(); } }
    else    { WAIT_VM0(); }             // tail: drain remaining loads
    S_BARRIER();                        // tile t+1 ready for all waves
  }

  float* outf = (float*)outp;
  short* outb = (short*)outp;
  #pragma unroll
  for (int j = 0; j < 4; j++) {
    const int col = n0 + wc * 64 + j * 16 + l16;
    const float bv = (OUTMODE == 3) ? 0.0f : bias[col];
    #pragma unroll
    for (int i = 0; i < MF; i++) {
      const int row0 = m0 + wr * (BM / 2) + i * 16 + kg * 4;
      #pragma unroll
      for (int e = 0; e < 4; e++) {
        float v = acc[i][j][e] + bv;
        if (OUTMODE == 2) v = fmaxf(v, 0.0f);
        const size_t off = (size_t)(row0 + e) * N + col;
        if (OUTMODE == 3) outf[off] = v;
        else              outb[off] = bf16r(v);
      }
    }
  }
}

// ---------------------------------------------------------------------------
// Fused flash attention. Block = 256 threads (4 waves), grid = (B*H, S/128).
// Each wave owns 32 q rows (2 row-tiles). K-frags read from global (L2-hot),
// V^T staged in LDS (64KB, XOR swizzle). Swapped QK^T.
// R22: s_setprio(1) around MFMA clusters (T5 — independent-wave regime,
// m191 measured +4-7%).
// ---------------------------------------------------------------------------
__launch_bounds__(256, 2)
__global__ void attn_kernel(const short* __restrict__ Qg, const short* __restrict__ Kg,
                            const short* __restrict__ Vg, const float* __restrict__ mask,
                            short* __restrict__ ctx) {
  __shared__ __align__(16) short Vt[64 * 512];   // [d][kv^swz], 64 KiB

  const int bh = blockIdx.x;            // 0..95
  const int b = bh / NH;
  const int h = bh % NH;
  const int tid  = threadIdx.x;
  const int lane = tid & 63;
  const int wid  = tid >> 6;
  const int l16  = lane & 15;
  const int kg   = lane >> 4;

  const short* Qb = Qg + (size_t)b * SEQ * DDIM + h * DHD;
  const short* Kb = Kg + (size_t)b * SEQ * DDIM + h * DHD;
  const short* Vb = Vg + (size_t)b * SEQ * DDIM + h * DHD;

  // stage V^T: Vt[d][kv ^ ((d&3)<<3)] = V[kv][d]
  for (int c = tid; c < SEQ * 8; c += 256) {
    const int kv = c >> 3;
    const int d0 = (c & 7) * 8;
    short8 v = *(const short8*)(Vb + (size_t)kv * DDIM + d0);
    #pragma unroll
    for (int j = 0; j < 8; j++)
      Vt[(d0 + j) * 512 + (kv ^ ((j & 3) << 3))] = v[j];
  }
  __syncthreads();

  const int q0 = blockIdx.y * 128 + wid * 32;

  // Q fragments (B operand: lane holds col q = l16, elems d = kg*8+j)
  short8 qf[2][2];
  #pragma unroll
  for (int rt = 0; rt < 2; rt++)
    #pragma unroll
    for (int dh = 0; dh < 2; dh++)
      qf[rt][dh] = *(const short8*)(Qb + (size_t)(q0 + rt * 16 + l16) * DDIM + dh * 32 + kg * 8);

  float mrun[2] = {-1e30f, -1e30f};
  float lrun[2] = {0.0f, 0.0f};
  const f32x4 zero = {0.f, 0.f, 0.f, 0.f};
  f32x4 oacc[2][4];
  #pragma unroll
  for (int rt = 0; rt < 2; rt++)
    #pragma unroll
    for (int dt = 0; dt < 4; dt++) oacc[rt][dt] = zero;

  const float* maskb = mask + (size_t)b * SEQ;

  for (int kv0 = 0; kv0 < SEQ; kv0 += 32) {
    // K fragments (A operand: lane holds row kv, elems d)
    short8 kf[2][2];
    #pragma unroll
    for (int kvh = 0; kvh < 2; kvh++)
      #pragma unroll
      for (int dh = 0; dh < 2; dh++)
        kf[kvh][dh] = *(const short8*)(Kb + (size_t)(kv0 + kvh * 16 + l16) * DDIM + dh * 32 + kg * 8);

    // V fragments (B operand of PV): lane holds col d = dt*16+l16, elems kv = kg*8+j
    short8 vf[4];
    #pragma unroll
    for (int dt = 0; dt < 4; dt++) {
      const int d = dt * 16 + l16;
      vf[dt] = *(const short8*)&Vt[d * 512 + ((kv0 + kg * 8) ^ ((d & 3) << 3))];
    }

    const f32x4 mq0 = *(const f32x4*)(maskb + kv0 + kg * 4);
    const f32x4 mq1 = *(const f32x4*)(maskb + kv0 + 16 + kg * 4);

    #pragma unroll
    for (int rt = 0; rt < 2; rt++) {
      f32x4 s0 = zero, s1 = zero;
      __builtin_amdgcn_s_setprio(1);
      s0 = mfma_bf16(kf[0][0], qf[rt][0], s0);
      s0 = mfma_bf16(kf[0][1], qf[rt][1], s0);
      s1 = mfma_bf16(kf[1][0], qf[rt][0], s1);
      s1 = mfma_bf16(kf[1][1], qf[rt][1], s1);
      __builtin_amdgcn_s_setprio(0);

      float p[8];
      #pragma unroll
      for (int e = 0; e < 4; e++) {
        p[e]     = s0[e] * 0.125f + mq0[e] * (-1e9f);
        p[e + 4] = s1[e] * 0.125f + mq1[e] * (-1e9f);
      }
      float mt = p[0];
      #pragma unroll
      for (int e = 1; e < 8; e++) mt = fmaxf(mt, p[e]);
      mt = fmaxf(mt, __shfl_xor(mt, 16, 64));
      mt = fmaxf(mt, __shfl_xor(mt, 32, 64));
      const float mnew = fmaxf(mrun[rt], mt);
      const float corr = __expf(mrun[rt] - mnew);
      float ts = 0.0f;
      #pragma unroll
      for (int e = 0; e < 8; e++) { p[e] = __expf(p[e] - mnew); ts += p[e]; }
      ts += __shfl_xor(ts, 16, 64);
      ts += __shfl_xor(ts, 32, 64);
      lrun[rt] = lrun[rt] * corr + ts;
      mrun[rt] = mnew;

      // pack p to bf16 pairs; redistribute to A-operand layout via shuffles
      const int P0 = (int)(((uint32_t)(uint16_t)bf16r(p[1]) << 16) | (uint16_t)bf16r(p[0]));
      const int P1 = (int)(((uint32_t)(uint16_t)bf16r(p[3]) << 16) | (uint16_t)bf16r(p[2]));
      const int P2 = (int)(((uint32_t)(uint16_t)bf16r(p[5]) << 16) | (uint16_t)bf16r(p[4]));
      const int P3 = (int)(((uint32_t)(uint16_t)bf16r(p[7]) << 16) | (uint16_t)bf16r(p[6]));
      const int sl0 = (((2 * kg) & 3) << 4) + l16;
      const int sl1 = (((2 * kg + 1) & 3) << 4) + l16;
      const int x0 = __shfl(P0, sl0, 64), y0 = __shfl(P2, sl0, 64);
      const int x1 = __shfl(P1, sl0, 64), y1 = __shfl(P3, sl0, 64);
      const int x2 = __shfl(P0, sl1, 64), y2 = __shfl(P2, sl1, 64);
      const int x3 = __shfl(P1, sl1, 64), y3 = __shfl(P3, sl1, 64);
      union { int w[4]; short8 v; } pa;
      const bool hi = (kg >= 2);
      pa.w[0] = hi ? y0 : x0;
      pa.w[1] = hi ? y1 : x1;
      pa.w[2] = hi ? y2 : x2;
      pa.w[3] = hi ? y3 : x3;

      // per-q-row rescale factors for O acc (O rows q = kg*4+e)
      const float c0 = __shfl(corr, kg * 4 + 0, 64);
      const float c1 = __shfl(corr, kg * 4 + 1, 64);
      const float c2 = __shfl(corr, kg * 4 + 2, 64);
      const float c3 = __shfl(corr, kg * 4 + 3, 64);

      __builtin_amdgcn_s_setprio(1);
      #pragma unroll
      for (int dt = 0; dt < 4; dt++) {
        f32x4 o = oacc[rt][dt];
        o[0] *= c0; o[1] *= c1; o[2] *= c2; o[3] *= c3;
        oacc[rt][dt] = mfma_bf16(pa.v, vf[dt], o);
      }
      __builtin_amdgcn_s_setprio(0);
    }
  }

  short* cb = ctx + (size_t)b * SEQ * DDIM + h * DHD;
  #pragma unroll
  for (int rt = 0; rt < 2; rt++) {
    const float li = 1.0f / lrun[rt];
    const float l0 = __shfl(li, kg * 4 + 0, 64);
    const float l1 = __shfl(li, kg * 4 + 1, 64);
    const float l2 = __shfl(li, kg * 4 + 2, 64);
    const float l3 = __shfl(li, kg * 4 + 3, 64);
    #pragma unroll
    for (int dt = 0; dt < 4; dt++) {
      const f32x4 o = oacc[rt][dt];
      const int col = dt * 16 + l16;
      const size_t base = (size_t)(q0 + rt * 16 + kg * 4) * DDIM + col;
      cb[base + 0 * DDIM] = bf16r(o[0] * l0);
      cb[base + 1 * DDIM] = bf16r(o[1] * l1);
      cb[base + 2 * DDIM] = bf16r(o[2] * l2);
      cb[base + 3 * DDIM] = bf16r(o[3] * l3);
    }
  }
}

// ---------------------------------------------------------------------------
// Fused split-K reduce + LayerNorm, float4-vectorized (G13):
// y = LN(resid + p0 + p1 + pbias) -> fp32 out + bf16 out.
// One wave per row; lane i covers cols {c*256 + i*4 .. +3}, c = 0..2.
// In-place safe (all reads into v[12] before any write).
// ---------------------------------------------------------------------------
__launch_bounds__(256, 4)
__global__ void ln_red_kernel(const float* __restrict__ resid,
                              const float* __restrict__ p0,
                              const float* __restrict__ p1,
                              const float* __restrict__ pb,
                              const float* __restrict__ gw,
                              const float* __restrict__ bw,
                              float* __restrict__ outf, short* __restrict__ outb) {
  const int lane = threadIdx.x & 63;
  const int wid  = threadIdx.x >> 6;
  const int row  = blockIdx.x * 4 + wid;
  const size_t base = (size_t)row * DDIM;
  float v[12];
  float s = 0.0f;
  #pragma unroll
  for (int c = 0; c < 3; c++) {
    const int col = c * 256 + lane * 4;
    const f32x4 r  = *(const f32x4*)(resid + base + col);
    const f32x4 q0 = *(const f32x4*)(p0 + base + col);
    const f32x4 q1 = *(const f32x4*)(p1 + base + col);
    const f32x4 bb = *(const f32x4*)(pb + col);
    #pragma unroll
    for (int j = 0; j < 4; j++) {
      const float a = r[j] + q0[j] + q1[j] + bb[j];
      v[c * 4 + j] = a;
      s += a;
    }
  }
  #pragma unroll
  for (int o = 1; o < 64; o <<= 1) s += __shfl_xor(s, o, 64);
  const float mean = s * (1.0f / 768.0f);
  float q = 0.0f;
  #pragma unroll
  for (int c = 0; c < 12; c++) { const float d = v[c] - mean; q += d * d; }
  #pragma unroll
  for (int o = 1; o < 64; o <<= 1) q += __shfl_xor(q, o, 64);
  const float inv = 1.0f / sqrtf(q * (1.0f / 768.0f) + 1e-5f);
  #pragma unroll
  for (int c = 0; c < 3; c++) {
    const int col = c * 256 + lane * 4;
    const f32x4 g4 = *(const f32x4*)(gw + col);
    const f32x4 b4 = *(const f32x4*)(bw + col);
    f32x4 y4;
    s16x4 o4;
    #pragma unroll
    for (int j = 0; j < 4; j++) {
      const float y = g4[j] * (v[c * 4 + j] - mean) * inv + b4[j];
      y4[j] = y;
      o4[j] = bf16r(y);
    }
    *(f32x4*)(outf + base + col) = y4;
    *(s16x4*)(outb + base + col) = o4;
  }
}

// ---------------------------------------------------------------------------
// Workspace (~84 MB):
//   H0   fp32 [4096][768]  residual stream (in-place LN)
//   Bbuf bf16 [4096][768]  bf16 of h / a
//   R1   bf16 [4096][3072] quarters: Q,K,V,ctx -> ffn1 full
//   WB   bf16 WLAYER       full layer: Wq|Wk|Wv|Wo|W1|W2 (one wconv launch)
//   P0,P1 fp32 [4096][768] split-K partial outputs (Oproj / FFN2)
// ---------------------------------------------------------------------------
extern "C" void kernel_launch(void* const* d_in, const int* in_sizes, int n_in,
                              void* d_out, int out_size, void* d_ws, size_t ws_size,
                              hipStream_t stream) {
  const float* x    = (const float*)d_in[0];
  const float* mask = (const float*)d_in[1];
  const float* Wq   = (const float*)d_in[2];
  const float* bq   = (const float*)d_in[3];
  const float* Wk   = (const float*)d_in[4];
  const float* bk   = (const float*)d_in[5];
  const float* Wv   = (const float*)d_in[6];
  const float* bv   = (const float*)d_in[7];
  const float* Wo   = (const float*)d_in[8];
  const float* bo   = (const float*)d_in[9];
  const float* g1   = (const float*)d_in[10];
  const float* b1   = (const float*)d_in[11];
  const float* W1   = (const float*)d_in[12];
  const float* bf1  = (const float*)d_in[13];
  const float* W2   = (const float*)d_in[14];
  const float* bf2  = (const float*)d_in[15];
  const float* g2   = (const float*)d_in[16];
  const float* b2   = (const float*)d_in[17];

  const size_t SD = (size_t)ROWS * DDIM;   // 3145728

  char* ws = (char*)d_ws;
  float* H0   = (float*)ws;  ws += SD * 4;                       // 12.58 MB
  short* Bbuf = (short*)ws;  ws += SD * 2;                       //  6.29 MB
  short* R1   = (short*)ws;  ws += (size_t)ROWS * DFF * 2;       // 25.17 MB
  short* WB   = (short*)ws;  ws += (size_t)(4 * WDD + 2 * WFD) * 2; // 14.16 MB
  float* P0   = (float*)ws;  ws += SD * 4;                       // 12.58 MB
  float* P1   = (float*)ws;                                      // 12.58 MB

  short* Qb = R1;
  short* Kb = R1 + SD;
  short* Vb = R1 + 2 * SD;
  short* Cb = R1 + 3 * SD;

  // x -> bf16
  xconv_kernel<<<dim3((int)(SD / 8 / 256)), 256, 0, stream>>>(x, Bbuf);

  for (int l = 0; l < NLAYER; l++) {
    // all six weight tensors of layer l in ONE launch
    {
      W6 w{};
      w.src[0] = Wq + (size_t)l * WDD;
      w.src[1] = Wk + (size_t)l * WDD;
      w.src[2] = Wv + (size_t)l * WDD;
      w.src[3] = Wo + (size_t)l * WDD;
      w.src[4] = W1 + (size_t)l * WFD;
      w.src[5] = W2 + (size_t)l * WFD;
      w.wb = WB;
      wconv6_kernel<<<dim3(1152, 6), 256, 0, stream>>>(w);
    }

    // QKV (fused via grid.z)
    {
      GemmB g{};
      g.W0 = WB;           g.b0 = bq + (size_t)l * DDIM; g.o0 = Qb;
      g.W1 = WB + WDD;     g.b1 = bk + (size_t)l * DDIM; g.o1 = Kb;
      g.W2 = WB + 2 * WDD; g.b2 = bv + (size_t)l * DDIM; g.o2 = Vb;
      gemm_bt<1, 128, 0><<<dim3(32, 6, 3), 256, 0, stream>>>(Bbuf, g, ROWS, DDIM, DDIM, DDIM);
    }

    // attention: ctx -> q3
    attn_kernel<<<dim3(NB * NH, 4), 256, 0, stream>>>(Qb, Kb, Vb, mask, Cb);

    // O projection, split-K2 -> P0,P1 (768 blocks = 3/CU)
    {
      GemmB g{};
      g.W0 = WB + 3 * WDD; g.b0 = bo; g.o0 = P0; g.o1 = P1;
      gemm_bt<3, 64, 1><<<dim3(64, 6, 2), 256, 0, stream>>>(Cb, g, ROWS, DDIM, DDIM, DDIM / 2);
    }

    // LN1 = reduce(P0+P1) + bias + LN(h + .) -> H0 (fp32) + Bbuf (bf16)
    ln_red_kernel<<<dim3(ROWS / 4), 256, 0, stream>>>(l ? H0 : x, P0, P1,
                                                      bo + (size_t)l * DDIM,
                                                      g1 + (size_t)l * DDIM, b1 + (size_t)l * DDIM,
                                                      H0, Bbuf);

    // FFN1 (bf16 + ReLU) -> R1 full
    {
      GemmB g{};
      g.W0 = WB + 4 * WDD; g.b0 = bf1 + (size_t)l * DFF; g.o0 = R1;
      gemm_bt<2, 128, 0><<<dim3(32, 24, 1), 256, 0, stream>>>(Bbuf, g, ROWS, DFF, DDIM, DDIM);
    }

    // FFN2, split-K2 -> P0,P1 (768 blocks, 48 steps each)
    {
      GemmB g{};
      g.W0 = WB + 4 * WDD + WFD; g.b0 = bf2; g.o0 = P0; g.o1 = P1;
      gemm_bt<3, 64, 1><<<dim3(64, 6, 2), 256, 0, stream>>>(R1, g, ROWS, DDIM, DFF, DFF / 2);
    }

    // LN2 = reduce(P0+P1) + bias + LN(a + .) -> H0 / d_out (fp32) + Bbuf (bf16)
    ln_red_kernel<<<dim3(ROWS / 4), 256, 0, stream>>>(H0, P0, P1,
                                                      bf2 + (size_t)l * DDIM,
                                                      g2 + (size_t)l * DDIM, b2 + (size_t)l * DDIM,
                                                      (l == NLAYER - 1) ? (float*)d_out : H0,
                                                      Bbuf);
  }
}

// Round 23
// 1898.159 us; speedup vs baseline: 1.0855x; 1.0190x over previous
//
#include <hip/hip_runtime.h>
#include <hip/hip_bf16.h>
#include <stdint.h>

#define DDIM 768
#define NH 12
#define DHD 64
#define DFF 3072
#define NLAYER 12
#define SEQ 512
#define NB 8
#define ROWS (NB*SEQ)   // 4096

typedef __attribute__((ext_vector_type(4))) float f32x4;
typedef __attribute__((ext_vector_type(8))) short short8;
typedef __attribute__((ext_vector_type(4))) short s16x4;

#define S_BARRIER()  asm volatile("s_barrier" ::: "memory")
#define WAIT_LGKM0() asm volatile("s_waitcnt lgkmcnt(0)" ::: "memory")
#define WAIT_VM0()   asm volatile("s_waitcnt vmcnt(0)" ::: "memory")
#define WAIT_VM3()   asm volatile("s_waitcnt vmcnt(3)" ::: "memory")
#define WAIT_VM4()   asm volatile("s_waitcnt vmcnt(4)" ::: "memory")

#define WDD    589824          // 768*768
#define WFD    2359296         // 3072*768

static __device__ __forceinline__ short bf16r(float f) {
  union { float f; uint32_t u; } a; a.f = f;
  uint32_t u = a.u;
  u += 0x7FFFu + ((u >> 16) & 1u);   // RNE
  return (short)(u >> 16);
}

static __device__ __forceinline__ float bf2f(short s) {
  union { uint32_t u; float f; } c;
  c.u = ((uint32_t)(uint16_t)s) << 16;
  return c.f;
}

static __device__ __forceinline__ f32x4 mfma_bf16(short8 a, short8 b, f32x4 c) {
  return __builtin_amdgcn_mfma_f32_16x16x32_bf16(a, b, c, 0, 0, 0);
}

// async global->LDS, 16B per lane. LDS dest is wave-uniform base; HW scatters
// lane i to base + i*16B. Global src is per-lane.
static __device__ __forceinline__ void gload16(const void* g, void* l) {
  __builtin_amdgcn_global_load_lds(
      (__attribute__((address_space(1))) void*)(void*)(uintptr_t)g,
      (__attribute__((address_space(3))) void*)l,
      16, 0, 0);
}

static __device__ __forceinline__ void cvt8(const float* __restrict__ s,
                                            short* __restrict__ d) {
  f32x4 a = *(const f32x4*)(s);
  f32x4 b = *(const f32x4*)(s + 4);
  short8 o;
  o[0] = bf16r(a[0]); o[1] = bf16r(a[1]); o[2] = bf16r(a[2]); o[3] = bf16r(a[3]);
  o[4] = bf16r(b[0]); o[5] = bf16r(b[1]); o[6] = bf16r(b[2]); o[7] = bf16r(b[3]);
  *(short8*)d = o;
}

// ---------------------------------------------------------------------------
// x fp32 -> bf16 (preamble)
// ---------------------------------------------------------------------------
__global__ void xconv_kernel(const float* __restrict__ src, short* __restrict__ dst) {
  const int i = blockIdx.x * 256 + threadIdx.x;   // grid covers ROWS*DDIM/8
  cvt8(src + (size_t)i * 8, dst + (size_t)i * 8);
}

// ---------------------------------------------------------------------------
// Per-layer weight conversion, ALL SIX tensors in ONE launch: grid (1152, 6).
// y = {Wq,Wk,Wv,Wo,W1,W2}; y<4 guards to 288 blocks' worth of chunks.
// WB layout: Wq|Wk|Wv|Wo|W1|W2 (full layer resident -> no aliasing order).
// ---------------------------------------------------------------------------
struct W6 {
  const float* src[6];   // layer-offset pointers
  short* wb;
};

__global__ void wconv6_kernel(W6 w) {
  const int y = blockIdx.y;
  const int n8 = (y < 4) ? (WDD / 8) : (WFD / 8);
  const int i = blockIdx.x * 256 + threadIdx.x;
  if (i >= n8) return;
  const int dstOff = (y < 4) ? y * WDD : 4 * WDD + (y - 4) * WFD;
  cvt8(w.src[y] + (size_t)i * 8, w.wb + dstOff + (size_t)i * 8);
}

// ---------------------------------------------------------------------------
// GEMM: C[M,N] = A[M,K] @ W[N,K]^T + bias   (bf16 in, fp32 acc, bf16 out)
// OUTMODE: 1 = +bias, 2 = +bias+ReLU, 3 = PARTIAL (no bias; split-K half,
// bf16 partial -- R23: halves split-K write + ln_red read traffic)
// BM x 128 tile, BK=32, 256 threads (4 waves, 2x2 wave grid).
// Counted-vmcnt pipeline (T4): depth-2 prefetch over 2 LDS buffers.
// SPLITK=1: blockIdx.z = K-half; partials to o0/o1 (R15's -131 us win).
// SPLITK=0: blockIdx.z selects (W, bias, out) triple (fused QKV).
// ---------------------------------------------------------------------------
struct GemmB {
  const short* W0; const short* W1; const short* W2;
  const float* b0; const float* b1; const float* b2;
  short* o0; short* o1; short* o2;
};

template<int OUTMODE, int BM, int SPLITK>
__launch_bounds__(256, 3)
__global__ void gemm_bt(const short* __restrict__ A, GemmB gb,
                        int M, int N, int Kstride, int Klen) {
  constexpr int MF  = BM / 32;   // row fragments per wave (4 or 2)
  constexpr int ISS = BM / 64;   // A staging issues per wave (2 or 1)

  const int z = blockIdx.z;
  const short* W;
  const float* bias;
  short* outb;
  if (SPLITK) {
    W    = gb.W0 + (size_t)z * Klen;       // column offset within each row
    bias = gb.b0;                          // unused (OUTMODE 3)
    outb = (z == 0) ? gb.o0 : gb.o1;
  } else {
    W    = (z == 0) ? gb.W0 : ((z == 1) ? gb.W1 : gb.W2);
    bias = (z == 0) ? gb.b0 : ((z == 1) ? gb.b1 : gb.b2);
    outb = (z == 0) ? gb.o0 : ((z == 1) ? gb.o1 : gb.o2);
  }

  __shared__ __align__(16) short As[2][BM * 32];
  __shared__ __align__(16) short Bs[2][128 * 32];

  const int tid  = threadIdx.x;
  const int lane = tid & 63;
  const int wid  = tid >> 6;
  const int l16  = lane & 15;
  const int kg   = lane >> 4;
  const int wr   = wid >> 1;
  const int wc   = wid & 1;
  const int m0   = blockIdx.x * BM;
  const int n0   = blockIdx.y * 128;

  const f32x4 zero = {0.f, 0.f, 0.f, 0.f};
  f32x4 acc[MF][4];
  #pragma unroll
  for (int i = 0; i < MF; i++)
    #pragma unroll
    for (int j = 0; j < 4; j++) acc[i][j] = zero;

  // staging: per issue, one wave covers 16 rows (64 lanes x 16B; 4 lanes/row)
  const int lrow = lane >> 2;          // 0..15
  const int lcol = (lane & 3) * 8;     // short offset within row
  const short* Ag = A + (size_t)(m0 + wid * (BM / 4) + lrow) * Kstride + lcol
                      + (SPLITK ? (size_t)z * Klen : 0);
  const short* Wg = W + (size_t)(n0 + wid * 32 + lrow) * Kstride + lcol;

  auto stage = [&](int buf, int k0) {
    #pragma unroll
    for (int j = 0; j < ISS; j++)
      gload16(Ag + k0 + (size_t)(j * 16) * Kstride, &As[buf][(wid * (BM / 4) + j * 16) * 32]);
    #pragma unroll
    for (int j = 0; j < 2; j++)
      gload16(Wg + k0 + (size_t)(j * 16) * Kstride, &Bs[buf][(wid * 32 + j * 16) * 32]);
  };

  const int nsteps = Klen >> 5;        // 12, 24, 48 or 96
  stage(0, 0);
  stage(1, 32);
  if (ISS == 2) { WAIT_VM4(); } else { WAIT_VM3(); }
  S_BARRIER();

  for (int t = 0; t < nsteps; ++t) {
    const int cur = t & 1;
    short8 af[MF], bfr[4];
    #pragma unroll
    for (int i = 0; i < MF; i++)
      af[i] = *(const short8*)&As[cur][(wr * (BM / 2) + i * 16 + l16) * 32 + kg * 8];
    #pragma unroll
    for (int j = 0; j < 4; j++)
      bfr[j] = *(const short8*)&Bs[cur][(wc * 64 + j * 16 + l16) * 32 + kg * 8];
    WAIT_LGKM0();                       // my reads of buf[cur] complete
    S_BARRIER();                        // all waves' reads complete -> reusable

    const bool pf = (t + 2 < nsteps);
    if (pf) stage(cur, (t + 2) << 5);   // overwrite consumed buffer
    __builtin_amdgcn_sched_barrier(0);  // MFMA stays after the stage issue
    #pragma unroll
    for (int i = 0; i < MF; i++)
      #pragma unroll
      for (int j = 0; j < 4; j++)
        acc[i][j] = mfma_bf16(af[i], bfr[j], acc[i][j]);
    __builtin_amdgcn_sched_barrier(0);  // MFMA stays before the vmcnt wait

    if (pf) { if (ISS == 2) { WAIT_VM4(); } else { WAIT_VM3(); } }
    else    { WAIT_VM0(); }             // tail: drain remaining loads
    S_BARRIER();                        // tile t+1 ready for all waves
  }

  #pragma unroll
  for (int j = 0; j < 4; j++) {
    const int col = n0 + wc * 64 + j * 16 + l16;
    const float bv = (OUTMODE == 3) ? 0.0f : bias[col];
    #pragma unroll
    for (int i = 0; i < MF; i++) {
      const int row0 = m0 + wr * (BM / 2) + i * 16 + kg * 4;
      #pragma unroll
      for (int e = 0; e < 4; e++) {
        float v = acc[i][j][e] + bv;
        if (OUTMODE == 2) v = fmaxf(v, 0.0f);
        outb[(size_t)(row0 + e) * N + col] = bf16r(v);
      }
    }
  }
}

// ---------------------------------------------------------------------------
// Fused flash attention. Block = 256 threads (4 waves), grid = (B*H, S/128).
// Each wave owns 32 q rows (2 row-tiles). K-frags read from global (L2-hot),
// V^T staged in LDS (64KB, XOR swizzle). Swapped QK^T.
// s_setprio(1) around MFMA clusters (T5 — R22's measured -10 us).
// ---------------------------------------------------------------------------
__launch_bounds__(256, 2)
__global__ void attn_kernel(const short* __restrict__ Qg, const short* __restrict__ Kg,
                            const short* __restrict__ Vg, const float* __restrict__ mask,
                            short* __restrict__ ctx) {
  __shared__ __align__(16) short Vt[64 * 512];   // [d][kv^swz], 64 KiB

  const int bh = blockIdx.x;            // 0..95
  const int b = bh / NH;
  const int h = bh % NH;
  const int tid  = threadIdx.x;
  const int lane = tid & 63;
  const int wid  = tid >> 6;
  const int l16  = lane & 15;
  const int kg   = lane >> 4;

  const short* Qb = Qg + (size_t)b * SEQ * DDIM + h * DHD;
  const short* Kb = Kg + (size_t)b * SEQ * DDIM + h * DHD;
  const short* Vb = Vg + (size_t)b * SEQ * DDIM + h * DHD;

  // stage V^T: Vt[d][kv ^ ((d&3)<<3)] = V[kv][d]
  for (int c = tid; c < SEQ * 8; c += 256) {
    const int kv = c >> 3;
    const int d0 = (c & 7) * 8;
    short8 v = *(const short8*)(Vb + (size_t)kv * DDIM + d0);
    #pragma unroll
    for (int j = 0; j < 8; j++)
      Vt[(d0 + j) * 512 + (kv ^ ((j & 3) << 3))] = v[j];
  }
  __syncthreads();

  const int q0 = blockIdx.y * 128 + wid * 32;

  // Q fragments (B operand: lane holds col q = l16, elems d = kg*8+j)
  short8 qf[2][2];
  #pragma unroll
  for (int rt = 0; rt < 2; rt++)
    #pragma unroll
    for (int dh = 0; dh < 2; dh++)
      qf[rt][dh] = *(const short8*)(Qb + (size_t)(q0 + rt * 16 + l16) * DDIM + dh * 32 + kg * 8);

  float mrun[2] = {-1e30f, -1e30f};
  float lrun[2] = {0.0f, 0.0f};
  const f32x4 zero = {0.f, 0.f, 0.f, 0.f};
  f32x4 oacc[2][4];
  #pragma unroll
  for (int rt = 0; rt < 2; rt++)
    #pragma unroll
    for (int dt = 0; dt < 4; dt++) oacc[rt][dt] = zero;

  const float* maskb = mask + (size_t)b * SEQ;

  for (int kv0 = 0; kv0 < SEQ; kv0 += 32) {
    // K fragments (A operand: lane holds row kv, elems d)
    short8 kf[2][2];
    #pragma unroll
    for (int kvh = 0; kvh < 2; kvh++)
      #pragma unroll
      for (int dh = 0; dh < 2; dh++)
        kf[kvh][dh] = *(const short8*)(Kb + (size_t)(kv0 + kvh * 16 + l16) * DDIM + dh * 32 + kg * 8);

    // V fragments (B operand of PV): lane holds col d = dt*16+l16, elems kv = kg*8+j
    short8 vf[4];
    #pragma unroll
    for (int dt = 0; dt < 4; dt++) {
      const int d = dt * 16 + l16;
      vf[dt] = *(const short8*)&Vt[d * 512 + ((kv0 + kg * 8) ^ ((d & 3) << 3))];
    }

    const f32x4 mq0 = *(const f32x4*)(maskb + kv0 + kg * 4);
    const f32x4 mq1 = *(const f32x4*)(maskb + kv0 + 16 + kg * 4);

    #pragma unroll
    for (int rt = 0; rt < 2; rt++) {
      f32x4 s0 = zero, s1 = zero;
      __builtin_amdgcn_s_setprio(1);
      s0 = mfma_bf16(kf[0][0], qf[rt][0], s0);
      s0 = mfma_bf16(kf[0][1], qf[rt][1], s0);
      s1 = mfma_bf16(kf[1][0], qf[rt][0], s1);
      s1 = mfma_bf16(kf[1][1], qf[rt][1], s1);
      __builtin_amdgcn_s_setprio(0);

      float p[8];
      #pragma unroll
      for (int e = 0; e < 4; e++) {
        p[e]     = s0[e] * 0.125f + mq0[e] * (-1e9f);
        p[e + 4] = s1[e] * 0.125f + mq1[e] * (-1e9f);
      }
      float mt = p[0];
      #pragma unroll
      for (int e = 1; e < 8; e++) mt = fmaxf(mt, p[e]);
      mt = fmaxf(mt, __shfl_xor(mt, 16, 64));
      mt = fmaxf(mt, __shfl_xor(mt, 32, 64));
      const float mnew = fmaxf(mrun[rt], mt);
      const float corr = __expf(mrun[rt] - mnew);
      float ts = 0.0f;
      #pragma unroll
      for (int e = 0; e < 8; e++) { p[e] = __expf(p[e] - mnew); ts += p[e]; }
      ts += __shfl_xor(ts, 16, 64);
      ts += __shfl_xor(ts, 32, 64);
      lrun[rt] = lrun[rt] * corr + ts;
      mrun[rt] = mnew;

      // pack p to bf16 pairs; redistribute to A-operand layout via shuffles
      const int P0 = (int)(((uint32_t)(uint16_t)bf16r(p[1]) << 16) | (uint16_t)bf16r(p[0]));
      const int P1 = (int)(((uint32_t)(uint16_t)bf16r(p[3]) << 16) | (uint16_t)bf16r(p[2]));
      const int P2 = (int)(((uint32_t)(uint16_t)bf16r(p[5]) << 16) | (uint16_t)bf16r(p[4]));
      const int P3 = (int)(((uint32_t)(uint16_t)bf16r(p[7]) << 16) | (uint16_t)bf16r(p[6]));
      const int sl0 = (((2 * kg) & 3) << 4) + l16;
      const int sl1 = (((2 * kg + 1) & 3) << 4) + l16;
      const int x0 = __shfl(P0, sl0, 64), y0 = __shfl(P2, sl0, 64);
      const int x1 = __shfl(P1, sl0, 64), y1 = __shfl(P3, sl0, 64);
      const int x2 = __shfl(P0, sl1, 64), y2 = __shfl(P2, sl1, 64);
      const int x3 = __shfl(P1, sl1, 64), y3 = __shfl(P3, sl1, 64);
      union { int w[4]; short8 v; } pa;
      const bool hi = (kg >= 2);
      pa.w[0] = hi ? y0 : x0;
      pa.w[1] = hi ? y1 : x1;
      pa.w[2] = hi ? y2 : x2;
      pa.w[3] = hi ? y3 : x3;

      // per-q-row rescale factors for O acc (O rows q = kg*4+e)
      const float c0 = __shfl(corr, kg * 4 + 0, 64);
      const float c1 = __shfl(corr, kg * 4 + 1, 64);
      const float c2 = __shfl(corr, kg * 4 + 2, 64);
      const float c3 = __shfl(corr, kg * 4 + 3, 64);

      __builtin_amdgcn_s_setprio(1);
      #pragma unroll
      for (int dt = 0; dt < 4; dt++) {
        f32x4 o = oacc[rt][dt];
        o[0] *= c0; o[1] *= c1; o[2] *= c2; o[3] *= c3;
        oacc[rt][dt] = mfma_bf16(pa.v, vf[dt], o);
      }
      __builtin_amdgcn_s_setprio(0);
    }
  }

  short* cb = ctx + (size_t)b * SEQ * DDIM + h * DHD;
  #pragma unroll
  for (int rt = 0; rt < 2; rt++) {
    const float li = 1.0f / lrun[rt];
    const float l0 = __shfl(li, kg * 4 + 0, 64);
    const float l1 = __shfl(li, kg * 4 + 1, 64);
    const float l2 = __shfl(li, kg * 4 + 2, 64);
    const float l3 = __shfl(li, kg * 4 + 3, 64);
    #pragma unroll
    for (int dt = 0; dt < 4; dt++) {
      const f32x4 o = oacc[rt][dt];
      const int col = dt * 16 + l16;
      const size_t base = (size_t)(q0 + rt * 16 + kg * 4) * DDIM + col;
      cb[base + 0 * DDIM] = bf16r(o[0] * l0);
      cb[base + 1 * DDIM] = bf16r(o[1] * l1);
      cb[base + 2 * DDIM] = bf16r(o[2] * l2);
      cb[base + 3 * DDIM] = bf16r(o[3] * l3);
    }
  }
}

// ---------------------------------------------------------------------------
// Fused split-K reduce + LayerNorm, vectorized (G13). R23: partials are bf16.
// y = LN(resid + p0 + p1 + pbias) -> fp32 out + bf16 out.
// One wave per row; lane i covers cols {c*256 + i*4 .. +3}, c = 0..2.
// In-place safe (all reads into v[12] before any write).
// ---------------------------------------------------------------------------
__launch_bounds__(256, 4)
__global__ void ln_red_kernel(const float* __restrict__ resid,
                              const short* __restrict__ p0,
                              const short* __restrict__ p1,
                              const float* __restrict__ pb,
                              const float* __restrict__ gw,
                              const float* __restrict__ bw,
                              float* __restrict__ outf, short* __restrict__ outb) {
  const int lane = threadIdx.x & 63;
  const int wid  = threadIdx.x >> 6;
  const int row  = blockIdx.x * 4 + wid;
  const size_t base = (size_t)row * DDIM;
  float v[12];
  float s = 0.0f;
  #pragma unroll
  for (int c = 0; c < 3; c++) {
    const int col = c * 256 + lane * 4;
    const f32x4 r  = *(const f32x4*)(resid + base + col);
    const s16x4 q0 = *(const s16x4*)(p0 + base + col);
    const s16x4 q1 = *(const s16x4*)(p1 + base + col);
    const f32x4 bb = *(const f32x4*)(pb + col);
    #pragma unroll
    for (int j = 0; j < 4; j++) {
      const float a = r[j] + bf2f(q0[j]) + bf2f(q1[j]) + bb[j];
      v[c * 4 + j] = a;
      s += a;
    }
  }
  #pragma unroll
  for (int o = 1; o < 64; o <<= 1) s += __shfl_xor(s, o, 64);
  const float mean = s * (1.0f / 768.0f);
  float q = 0.0f;
  #pragma unroll
  for (int c = 0; c < 12; c++) { const float d = v[c] - mean; q += d * d; }
  #pragma unroll
  for (int o = 1; o < 64; o <<= 1) q += __shfl_xor(q, o, 64);
  const float inv = 1.0f / sqrtf(q * (1.0f / 768.0f) + 1e-5f);
  #pragma unroll
  for (int c = 0; c < 3; c++) {
    const int col = c * 256 + lane * 4;
    const f32x4 g4 = *(const f32x4*)(gw + col);
    const f32x4 b4 = *(const f32x4*)(bw + col);
    f32x4 y4;
    s16x4 o4;
    #pragma unroll
    for (int j = 0; j < 4; j++) {
      const float y = g4[j] * (v[c * 4 + j] - mean) * inv + b4[j];
      y4[j] = y;
      o4[j] = bf16r(y);
    }
    *(f32x4*)(outf + base + col) = y4;
    *(s16x4*)(outb + base + col) = o4;
  }
}

// ---------------------------------------------------------------------------
// Workspace (~71 MB):
//   H0   fp32 [4096][768]  residual stream (in-place LN)
//   Bbuf bf16 [4096][768]  bf16 of h / a
//   R1   bf16 [4096][3072] quarters: Q,K,V,ctx -> ffn1 full
//   WB   bf16 WLAYER       full layer: Wq|Wk|Wv|Wo|W1|W2 (one wconv launch)
//   P0,P1 bf16 [4096][768] split-K partial outputs (R23: bf16, was fp32)
// ---------------------------------------------------------------------------
extern "C" void kernel_launch(void* const* d_in, const int* in_sizes, int n_in,
                              void* d_out, int out_size, void* d_ws, size_t ws_size,
                              hipStream_t stream) {
  const float* x    = (const float*)d_in[0];
  const float* mask = (const float*)d_in[1];
  const float* Wq   = (const float*)d_in[2];
  const float* bq   = (const float*)d_in[3];
  const float* Wk   = (const float*)d_in[4];
  const float* bk   = (const float*)d_in[5];
  const float* Wv   = (const float*)d_in[6];
  const float* bv   = (const float*)d_in[7];
  const float* Wo   = (const float*)d_in[8];
  const float* bo   = (const float*)d_in[9];
  const float* g1   = (const float*)d_in[10];
  const float* b1   = (const float*)d_in[11];
  const float* W1   = (const float*)d_in[12];
  const float* bf1  = (const float*)d_in[13];
  const float* W2   = (const float*)d_in[14];
  const float* bf2  = (const float*)d_in[15];
  const float* g2   = (const float*)d_in[16];
  const float* b2   = (const float*)d_in[17];

  const size_t SD = (size_t)ROWS * DDIM;   // 3145728

  char* ws = (char*)d_ws;
  float* H0   = (float*)ws;  ws += SD * 4;                       // 12.58 MB
  short* Bbuf = (short*)ws;  ws += SD * 2;                       //  6.29 MB
  short* R1   = (short*)ws;  ws += (size_t)ROWS * DFF * 2;       // 25.17 MB
  short* WB   = (short*)ws;  ws += (size_t)(4 * WDD + 2 * WFD) * 2; // 14.16 MB
  short* P0   = (short*)ws;  ws += SD * 2;                       //  6.29 MB
  short* P1   = (short*)ws;                                      //  6.29 MB

  short* Qb = R1;
  short* Kb = R1 + SD;
  short* Vb = R1 + 2 * SD;
  short* Cb = R1 + 3 * SD;

  // x -> bf16
  xconv_kernel<<<dim3((int)(SD / 8 / 256)), 256, 0, stream>>>(x, Bbuf);

  for (int l = 0; l < NLAYER; l++) {
    // all six weight tensors of layer l in ONE launch
    {
      W6 w{};
      w.src[0] = Wq + (size_t)l * WDD;
      w.src[1] = Wk + (size_t)l * WDD;
      w.src[2] = Wv + (size_t)l * WDD;
      w.src[3] = Wo + (size_t)l * WDD;
      w.src[4] = W1 + (size_t)l * WFD;
      w.src[5] = W2 + (size_t)l * WFD;
      w.wb = WB;
      wconv6_kernel<<<dim3(1152, 6), 256, 0, stream>>>(w);
    }

    // QKV (fused via grid.z)
    {
      GemmB g{};
      g.W0 = WB;           g.b0 = bq + (size_t)l * DDIM; g.o0 = Qb;
      g.W1 = WB + WDD;     g.b1 = bk + (size_t)l * DDIM; g.o1 = Kb;
      g.W2 = WB + 2 * WDD; g.b2 = bv + (size_t)l * DDIM; g.o2 = Vb;
      gemm_bt<1, 128, 0><<<dim3(32, 6, 3), 256, 0, stream>>>(Bbuf, g, ROWS, DDIM, DDIM, DDIM);
    }

    // attention: ctx -> q3
    attn_kernel<<<dim3(NB * NH, 4), 256, 0, stream>>>(Qb, Kb, Vb, mask, Cb);

    // O projection, split-K2 -> P0,P1 (768 blocks = 3/CU; bf16 partials)
    {
      GemmB g{};
      g.W0 = WB + 3 * WDD; g.b0 = bo; g.o0 = P0; g.o1 = P1;
      gemm_bt<3, 64, 1><<<dim3(64, 6, 2), 256, 0, stream>>>(Cb, g, ROWS, DDIM, DDIM, DDIM / 2);
    }

    // LN1 = reduce(P0+P1) + bias + LN(h + .) -> H0 (fp32) + Bbuf (bf16)
    ln_red_kernel<<<dim3(ROWS / 4), 256, 0, stream>>>(l ? H0 : x, P0, P1,
                                                      bo + (size_t)l * DDIM,
                                                      g1 + (size_t)l * DDIM, b1 + (size_t)l * DDIM,
                                                      H0, Bbuf);

    // FFN1 (bf16 + ReLU) -> R1 full
    {
      GemmB g{};
      g.W0 = WB + 4 * WDD; g.b0 = bf1 + (size_t)l * DFF; g.o0 = R1;
      gemm_bt<2, 128, 0><<<dim3(32, 24, 1), 256, 0, stream>>>(Bbuf, g, ROWS, DFF, DDIM, DDIM);
    }

    // FFN2, split-K2 -> P0,P1 (768 blocks, 48 steps each; bf16 partials)
    {
      GemmB g{};
      g.W0 = WB + 4 * WDD + WFD; g.b0 = bf2; g.o0 = P0; g.o1 = P1;
      gemm_bt<3, 64, 1><<<dim3(64, 6, 2), 256, 0, stream>>>(R1, g, ROWS, DDIM, DFF, DFF / 2);
    }

    // LN2 = reduce(P0+P1) + bias + LN(a + .) -> H0 / d_out (fp32) + Bbuf (bf16)
    ln_red_kernel<<<dim3(ROWS / 4), 256, 0, stream>>>(H0, P0, P1,
                                                      bf2 + (size_t)l * DDIM,
                                                      g2 + (size_t)l * DDIM, b2 + (size_t)l * DDIM,
                                                      (l == NLAYER - 1) ? (float*)d_out : H0,
                                                      Bbuf);
  }
}

// Round 24
// 1849.719 us; speedup vs baseline: 1.1140x; 1.0262x over previous
//
#include <hip/hip_runtime.h>
#include <hip/hip_bf16.h>
#include <stdint.h>

#define DDIM 768
#define NH 12
#define DHD 64
#define DFF 3072
#define NLAYER 12
#define SEQ 512
#define NB 8
#define ROWS (NB*SEQ)   // 4096

typedef __attribute__((ext_vector_type(4))) float f32x4;
typedef __attribute__((ext_vector_type(8))) short short8;
typedef __attribute__((ext_vector_type(4))) short s16x4;

#define S_BARRIER()  asm volatile("s_barrier" ::: "memory")
#define WAIT_LGKM0() asm volatile("s_waitcnt lgkmcnt(0)" ::: "memory")
#define WAIT_VM0()   asm volatile("s_waitcnt vmcnt(0)" ::: "memory")
#define WAIT_VM3()   asm volatile("s_waitcnt vmcnt(3)" ::: "memory")
#define WAIT_VM4()   asm volatile("s_waitcnt vmcnt(4)" ::: "memory")

#define WDD    589824          // 768*768
#define WFD    2359296         // 3072*768

static __device__ __forceinline__ short bf16r(float f) {
  union { float f; uint32_t u; } a; a.f = f;
  uint32_t u = a.u;
  u += 0x7FFFu + ((u >> 16) & 1u);   // RNE
  return (short)(u >> 16);
}

static __device__ __forceinline__ float bf2f(short s) {
  union { uint32_t u; float f; } c;
  c.u = ((uint32_t)(uint16_t)s) << 16;
  return c.f;
}

static __device__ __forceinline__ f32x4 mfma_bf16(short8 a, short8 b, f32x4 c) {
  return __builtin_amdgcn_mfma_f32_16x16x32_bf16(a, b, c, 0, 0, 0);
}

// async global->LDS, 16B per lane. LDS dest is wave-uniform base; HW scatters
// lane i to base + i*16B. Global src is per-lane.
static __device__ __forceinline__ void gload16(const void* g, void* l) {
  __builtin_amdgcn_global_load_lds(
      (__attribute__((address_space(1))) void*)(void*)(uintptr_t)g,
      (__attribute__((address_space(3))) void*)l,
      16, 0, 0);
}

static __device__ __forceinline__ void cvt8(const float* __restrict__ s,
                                            short* __restrict__ d) {
  f32x4 a = *(const f32x4*)(s);
  f32x4 b = *(const f32x4*)(s + 4);
  short8 o;
  o[0] = bf16r(a[0]); o[1] = bf16r(a[1]); o[2] = bf16r(a[2]); o[3] = bf16r(a[3]);
  o[4] = bf16r(b[0]); o[5] = bf16r(b[1]); o[6] = bf16r(b[2]); o[7] = bf16r(b[3]);
  *(short8*)d = o;
}

// ---------------------------------------------------------------------------
// x fp32 -> bf16 (preamble)
// ---------------------------------------------------------------------------
__global__ void xconv_kernel(const float* __restrict__ src, short* __restrict__ dst) {
  const int i = blockIdx.x * 256 + threadIdx.x;   // grid covers ROWS*DDIM/8
  cvt8(src + (size_t)i * 8, dst + (size_t)i * 8);
}

// ---------------------------------------------------------------------------
// Per-layer weight conversion, ALL SIX tensors in ONE launch: grid (1152, 6).
// y = {Wq,Wk,Wv,Wo,W1,W2}; y<4 guards to 288 blocks' worth of chunks.
// WB layout: Wq|Wk|Wv|Wo|W1|W2 (full layer resident -> no aliasing order).
// ---------------------------------------------------------------------------
struct W6 {
  const float* src[6];   // layer-offset pointers
  short* wb;
};

__global__ void wconv6_kernel(W6 w) {
  const int y = blockIdx.y;
  const int n8 = (y < 4) ? (WDD / 8) : (WFD / 8);
  const int i = blockIdx.x * 256 + threadIdx.x;
  if (i >= n8) return;
  const int dstOff = (y < 4) ? y * WDD : 4 * WDD + (y - 4) * WFD;
  cvt8(w.src[y] + (size_t)i * 8, w.wb + dstOff + (size_t)i * 8);
}

// ---------------------------------------------------------------------------
// GEMM: C[M,N] = A[M,K] @ W[N,K]^T + bias   (bf16 in, fp32 acc, bf16 out)
// OUTMODE: 1 = +bias, 2 = +bias+ReLU, 3 = PARTIAL (no bias; split-K half,
// bf16 partial -- R23's measured -36 us)
// BM x 128 tile, BK=32, 256 threads (4 waves, 2x2 wave grid).
// Counted-vmcnt pipeline (T4): depth-2 prefetch over 2 LDS buffers.
// SPLITK=1: blockIdx.z = K-half; partials to o0/o1 (R15's -131 us win).
// SPLITK=0: blockIdx.z selects (W, bias, out) triple (fused QKV).
// ---------------------------------------------------------------------------
struct GemmB {
  const short* W0; const short* W1; const short* W2;
  const float* b0; const float* b1; const float* b2;
  short* o0; short* o1; short* o2;
};

template<int OUTMODE, int BM, int SPLITK>
__launch_bounds__(256, 3)
__global__ void gemm_bt(const short* __restrict__ A, GemmB gb,
                        int M, int N, int Kstride, int Klen) {
  constexpr int MF  = BM / 32;   // row fragments per wave (4 or 2)
  constexpr int ISS = BM / 64;   // A staging issues per wave (2 or 1)

  const int z = blockIdx.z;
  const short* W;
  const float* bias;
  short* outb;
  if (SPLITK) {
    W    = gb.W0 + (size_t)z * Klen;       // column offset within each row
    bias = gb.b0;                          // unused (OUTMODE 3)
    outb = (z == 0) ? gb.o0 : gb.o1;
  } else {
    W    = (z == 0) ? gb.W0 : ((z == 1) ? gb.W1 : gb.W2);
    bias = (z == 0) ? gb.b0 : ((z == 1) ? gb.b1 : gb.b2);
    outb = (z == 0) ? gb.o0 : ((z == 1) ? gb.o1 : gb.o2);
  }

  __shared__ __align__(16) short As[2][BM * 32];
  __shared__ __align__(16) short Bs[2][128 * 32];

  const int tid  = threadIdx.x;
  const int lane = tid & 63;
  const int wid  = tid >> 6;
  const int l16  = lane & 15;
  const int kg   = lane >> 4;
  const int wr   = wid >> 1;
  const int wc   = wid & 1;
  const int m0   = blockIdx.x * BM;
  const int n0   = blockIdx.y * 128;

  const f32x4 zero = {0.f, 0.f, 0.f, 0.f};
  f32x4 acc[MF][4];
  #pragma unroll
  for (int i = 0; i < MF; i++)
    #pragma unroll
    for (int j = 0; j < 4; j++) acc[i][j] = zero;

  // staging: per issue, one wave covers 16 rows (64 lanes x 16B; 4 lanes/row)
  const int lrow = lane >> 2;          // 0..15
  const int lcol = (lane & 3) * 8;     // short offset within row
  const short* Ag = A + (size_t)(m0 + wid * (BM / 4) + lrow) * Kstride + lcol
                      + (SPLITK ? (size_t)z * Klen : 0);
  const short* Wg = W + (size_t)(n0 + wid * 32 + lrow) * Kstride + lcol;

  auto stage = [&](int buf, int k0) {
    #pragma unroll
    for (int j = 0; j < ISS; j++)
      gload16(Ag + k0 + (size_t)(j * 16) * Kstride, &As[buf][(wid * (BM / 4) + j * 16) * 32]);
    #pragma unroll
    for (int j = 0; j < 2; j++)
      gload16(Wg + k0 + (size_t)(j * 16) * Kstride, &Bs[buf][(wid * 32 + j * 16) * 32]);
  };

  const int nsteps = Klen >> 5;        // 12, 24, 48 or 96
  stage(0, 0);
  stage(1, 32);
  if (ISS == 2) { WAIT_VM4(); } else { WAIT_VM3(); }
  S_BARRIER();

  for (int t = 0; t < nsteps; ++t) {
    const int cur = t & 1;
    short8 af[MF], bfr[4];
    #pragma unroll
    for (int i = 0; i < MF; i++)
      af[i] = *(const short8*)&As[cur][(wr * (BM / 2) + i * 16 + l16) * 32 + kg * 8];
    #pragma unroll
    for (int j = 0; j < 4; j++)
      bfr[j] = *(const short8*)&Bs[cur][(wc * 64 + j * 16 + l16) * 32 + kg * 8];
    WAIT_LGKM0();                       // my reads of buf[cur] complete
    S_BARRIER();                        // all waves' reads complete -> reusable

    const bool pf = (t + 2 < nsteps);
    if (pf) stage(cur, (t + 2) << 5);   // overwrite consumed buffer
    __builtin_amdgcn_sched_barrier(0);  // MFMA stays after the stage issue
    #pragma unroll
    for (int i = 0; i < MF; i++)
      #pragma unroll
      for (int j = 0; j < 4; j++)
        acc[i][j] = mfma_bf16(af[i], bfr[j], acc[i][j]);
    __builtin_amdgcn_sched_barrier(0);  // MFMA stays before the vmcnt wait

    if (pf) { if (ISS == 2) { WAIT_VM4(); } else { WAIT_VM3(); } }
    else    { WAIT_VM0(); }             // tail: drain remaining loads
    S_BARRIER();                        // tile t+1 ready for all waves
  }

  #pragma unroll
  for (int j = 0; j < 4; j++) {
    const int col = n0 + wc * 64 + j * 16 + l16;
    const float bv = (OUTMODE == 3) ? 0.0f : bias[col];
    #pragma unroll
    for (int i = 0; i < MF; i++) {
      const int row0 = m0 + wr * (BM / 2) + i * 16 + kg * 4;
      #pragma unroll
      for (int e = 0; e < 4; e++) {
        float v = acc[i][j][e] + bv;
        if (OUTMODE == 2) v = fmaxf(v, 0.0f);
        outb[(size_t)(row0 + e) * N + col] = bf16r(v);
      }
    }
  }
}

// ---------------------------------------------------------------------------
// Fused flash attention. Block = 256 threads (4 waves), grid = (B*H, S/128).
// Each wave owns 32 q rows (2 row-tiles). K-frags read from global (L2-hot),
// V^T staged in LDS (64KB, XOR swizzle). Swapped QK^T.
// s_setprio(1) around MFMA clusters (T5 — R22's measured -10 us).
// ---------------------------------------------------------------------------
__launch_bounds__(256, 2)
__global__ void attn_kernel(const short* __restrict__ Qg, const short* __restrict__ Kg,
                            const short* __restrict__ Vg, const float* __restrict__ mask,
                            short* __restrict__ ctx) {
  __shared__ __align__(16) short Vt[64 * 512];   // [d][kv^swz], 64 KiB

  const int bh = blockIdx.x;            // 0..95
  const int b = bh / NH;
  const int h = bh % NH;
  const int tid  = threadIdx.x;
  const int lane = tid & 63;
  const int wid  = tid >> 6;
  const int l16  = lane & 15;
  const int kg   = lane >> 4;

  const short* Qb = Qg + (size_t)b * SEQ * DDIM + h * DHD;
  const short* Kb = Kg + (size_t)b * SEQ * DDIM + h * DHD;
  const short* Vb = Vg + (size_t)b * SEQ * DDIM + h * DHD;

  // stage V^T: Vt[d][kv ^ ((d&3)<<3)] = V[kv][d]
  for (int c = tid; c < SEQ * 8; c += 256) {
    const int kv = c >> 3;
    const int d0 = (c & 7) * 8;
    short8 v = *(const short8*)(Vb + (size_t)kv * DDIM + d0);
    #pragma unroll
    for (int j = 0; j < 8; j++)
      Vt[(d0 + j) * 512 + (kv ^ ((j & 3) << 3))] = v[j];
  }
  __syncthreads();

  const int q0 = blockIdx.y * 128 + wid * 32;

  // Q fragments (B operand: lane holds col q = l16, elems d = kg*8+j)
  short8 qf[2][2];
  #pragma unroll
  for (int rt = 0; rt < 2; rt++)
    #pragma unroll
    for (int dh = 0; dh < 2; dh++)
      qf[rt][dh] = *(const short8*)(Qb + (size_t)(q0 + rt * 16 + l16) * DDIM + dh * 32 + kg * 8);

  float mrun[2] = {-1e30f, -1e30f};
  float lrun[2] = {0.0f, 0.0f};
  const f32x4 zero = {0.f, 0.f, 0.f, 0.f};
  f32x4 oacc[2][4];
  #pragma unroll
  for (int rt = 0; rt < 2; rt++)
    #pragma unroll
    for (int dt = 0; dt < 4; dt++) oacc[rt][dt] = zero;

  const float* maskb = mask + (size_t)b * SEQ;

  for (int kv0 = 0; kv0 < SEQ; kv0 += 32) {
    // K fragments (A operand: lane holds row kv, elems d)
    short8 kf[2][2];
    #pragma unroll
    for (int kvh = 0; kvh < 2; kvh++)
      #pragma unroll
      for (int dh = 0; dh < 2; dh++)
        kf[kvh][dh] = *(const short8*)(Kb + (size_t)(kv0 + kvh * 16 + l16) * DDIM + dh * 32 + kg * 8);

    // V fragments (B operand of PV): lane holds col d = dt*16+l16, elems kv = kg*8+j
    short8 vf[4];
    #pragma unroll
    for (int dt = 0; dt < 4; dt++) {
      const int d = dt * 16 + l16;
      vf[dt] = *(const short8*)&Vt[d * 512 + ((kv0 + kg * 8) ^ ((d & 3) << 3))];
    }

    const f32x4 mq0 = *(const f32x4*)(maskb + kv0 + kg * 4);
    const f32x4 mq1 = *(const f32x4*)(maskb + kv0 + 16 + kg * 4);

    #pragma unroll
    for (int rt = 0; rt < 2; rt++) {
      f32x4 s0 = zero, s1 = zero;
      __builtin_amdgcn_s_setprio(1);
      s0 = mfma_bf16(kf[0][0], qf[rt][0], s0);
      s0 = mfma_bf16(kf[0][1], qf[rt][1], s0);
      s1 = mfma_bf16(kf[1][0], qf[rt][0], s1);
      s1 = mfma_bf16(kf[1][1], qf[rt][1], s1);
      __builtin_amdgcn_s_setprio(0);

      float p[8];
      #pragma unroll
      for (int e = 0; e < 4; e++) {
        p[e]     = s0[e] * 0.125f + mq0[e] * (-1e9f);
        p[e + 4] = s1[e] * 0.125f + mq1[e] * (-1e9f);
      }
      float mt = p[0];
      #pragma unroll
      for (int e = 1; e < 8; e++) mt = fmaxf(mt, p[e]);
      mt = fmaxf(mt, __shfl_xor(mt, 16, 64));
      mt = fmaxf(mt, __shfl_xor(mt, 32, 64));
      const float mnew = fmaxf(mrun[rt], mt);
      const float corr = __expf(mrun[rt] - mnew);
      float ts = 0.0f;
      #pragma unroll
      for (int e = 0; e < 8; e++) { p[e] = __expf(p[e] - mnew); ts += p[e]; }
      ts += __shfl_xor(ts, 16, 64);
      ts += __shfl_xor(ts, 32, 64);
      lrun[rt] = lrun[rt] * corr + ts;
      mrun[rt] = mnew;

      // pack p to bf16 pairs; redistribute to A-operand layout via shuffles
      const int P0 = (int)(((uint32_t)(uint16_t)bf16r(p[1]) << 16) | (uint16_t)bf16r(p[0]));
      const int P1 = (int)(((uint32_t)(uint16_t)bf16r(p[3]) << 16) | (uint16_t)bf16r(p[2]));
      const int P2 = (int)(((uint32_t)(uint16_t)bf16r(p[5]) << 16) | (uint16_t)bf16r(p[4]));
      const int P3 = (int)(((uint32_t)(uint16_t)bf16r(p[7]) << 16) | (uint16_t)bf16r(p[6]));
      const int sl0 = (((2 * kg) & 3) << 4) + l16;
      const int sl1 = (((2 * kg + 1) & 3) << 4) + l16;
      const int x0 = __shfl(P0, sl0, 64), y0 = __shfl(P2, sl0, 64);
      const int x1 = __shfl(P1, sl0, 64), y1 = __shfl(P3, sl0, 64);
      const int x2 = __shfl(P0, sl1, 64), y2 = __shfl(P2, sl1, 64);
      const int x3 = __shfl(P1, sl1, 64), y3 = __shfl(P3, sl1, 64);
      union { int w[4]; short8 v; } pa;
      const bool hi = (kg >= 2);
      pa.w[0] = hi ? y0 : x0;
      pa.w[1] = hi ? y1 : x1;
      pa.w[2] = hi ? y2 : x2;
      pa.w[3] = hi ? y3 : x3;

      // per-q-row rescale factors for O acc (O rows q = kg*4+e)
      const float c0 = __shfl(corr, kg * 4 + 0, 64);
      const float c1 = __shfl(corr, kg * 4 + 1, 64);
      const float c2 = __shfl(corr, kg * 4 + 2, 64);
      const float c3 = __shfl(corr, kg * 4 + 3, 64);

      __builtin_amdgcn_s_setprio(1);
      #pragma unroll
      for (int dt = 0; dt < 4; dt++) {
        f32x4 o = oacc[rt][dt];
        o[0] *= c0; o[1] *= c1; o[2] *= c2; o[3] *= c3;
        oacc[rt][dt] = mfma_bf16(pa.v, vf[dt], o);
      }
      __builtin_amdgcn_s_setprio(0);
    }
  }

  short* cb = ctx + (size_t)b * SEQ * DDIM + h * DHD;
  #pragma unroll
  for (int rt = 0; rt < 2; rt++) {
    const float li = 1.0f / lrun[rt];
    const float l0 = __shfl(li, kg * 4 + 0, 64);
    const float l1 = __shfl(li, kg * 4 + 1, 64);
    const float l2 = __shfl(li, kg * 4 + 2, 64);
    const float l3 = __shfl(li, kg * 4 + 3, 64);
    #pragma unroll
    for (int dt = 0; dt < 4; dt++) {
      const f32x4 o = oacc[rt][dt];
      const int col = dt * 16 + l16;
      const size_t base = (size_t)(q0 + rt * 16 + kg * 4) * DDIM + col;
      cb[base + 0 * DDIM] = bf16r(o[0] * l0);
      cb[base + 1 * DDIM] = bf16r(o[1] * l1);
      cb[base + 2 * DDIM] = bf16r(o[2] * l2);
      cb[base + 3 * DDIM] = bf16r(o[3] * l3);
    }
  }
}

// ---------------------------------------------------------------------------
// Fused split-K reduce + LayerNorm, vectorized (G13). R24: resid is bf16 too;
// output is a single bf16 stream (serves as GEMM input AND next residual).
// y = LN(resid + p0 + p1 + pbias) -> bf16 out (+ fp32 out if OUTF32, final).
// One wave per row; lane i covers cols {c*256 + i*4 .. +3}, c = 0..2.
// Safe: resid and out are DIFFERENT buffers (hb/ab alternate).
// ---------------------------------------------------------------------------
template<int OUTF32>
__launch_bounds__(256, 4)
__global__ void ln_red_kernel(const short* __restrict__ resid,
                              const short* __restrict__ p0,
                              const short* __restrict__ p1,
                              const float* __restrict__ pb,
                              const float* __restrict__ gw,
                              const float* __restrict__ bw,
                              short* __restrict__ outb, float* __restrict__ outf) {
  const int lane = threadIdx.x & 63;
  const int wid  = threadIdx.x >> 6;
  const int row  = blockIdx.x * 4 + wid;
  const size_t base = (size_t)row * DDIM;
  float v[12];
  float s = 0.0f;
  #pragma unroll
  for (int c = 0; c < 3; c++) {
    const int col = c * 256 + lane * 4;
    const s16x4 r  = *(const s16x4*)(resid + base + col);
    const s16x4 q0 = *(const s16x4*)(p0 + base + col);
    const s16x4 q1 = *(const s16x4*)(p1 + base + col);
    const f32x4 bb = *(const f32x4*)(pb + col);
    #pragma unroll
    for (int j = 0; j < 4; j++) {
      const float a = bf2f(r[j]) + bf2f(q0[j]) + bf2f(q1[j]) + bb[j];
      v[c * 4 + j] = a;
      s += a;
    }
  }
  #pragma unroll
  for (int o = 1; o < 64; o <<= 1) s += __shfl_xor(s, o, 64);
  const float mean = s * (1.0f / 768.0f);
  float q = 0.0f;
  #pragma unroll
  for (int c = 0; c < 12; c++) { const float d = v[c] - mean; q += d * d; }
  #pragma unroll
  for (int o = 1; o < 64; o <<= 1) q += __shfl_xor(q, o, 64);
  const float inv = 1.0f / sqrtf(q * (1.0f / 768.0f) + 1e-5f);
  #pragma unroll
  for (int c = 0; c < 3; c++) {
    const int col = c * 256 + lane * 4;
    const f32x4 g4 = *(const f32x4*)(gw + col);
    const f32x4 b4 = *(const f32x4*)(bw + col);
    f32x4 y4;
    s16x4 o4;
    #pragma unroll
    for (int j = 0; j < 4; j++) {
      const float y = g4[j] * (v[c * 4 + j] - mean) * inv + b4[j];
      y4[j] = y;
      o4[j] = bf16r(y);
    }
    *(s16x4*)(outb + base + col) = o4;
    if (OUTF32) *(f32x4*)(outf + base + col) = y4;
  }
}

// ---------------------------------------------------------------------------
// Workspace (~65 MB):
//   hb,ab bf16 [4096][768] residual stream, alternating (R24: fp32 H0 gone)
//   R1   bf16 [4096][3072] quarters: Q,K,V,ctx -> ffn1 full
//   WB   bf16 WLAYER       full layer: Wq|Wk|Wv|Wo|W1|W2 (one wconv launch)
//   P0,P1 bf16 [4096][768] split-K partial outputs
// ---------------------------------------------------------------------------
extern "C" void kernel_launch(void* const* d_in, const int* in_sizes, int n_in,
                              void* d_out, int out_size, void* d_ws, size_t ws_size,
                              hipStream_t stream) {
  const float* x    = (const float*)d_in[0];
  const float* mask = (const float*)d_in[1];
  const float* Wq   = (const float*)d_in[2];
  const float* bq   = (const float*)d_in[3];
  const float* Wk   = (const float*)d_in[4];
  const float* bk   = (const float*)d_in[5];
  const float* Wv   = (const float*)d_in[6];
  const float* bv   = (const float*)d_in[7];
  const float* Wo   = (const float*)d_in[8];
  const float* bo   = (const float*)d_in[9];
  const float* g1   = (const float*)d_in[10];
  const float* b1   = (const float*)d_in[11];
  const float* W1   = (const float*)d_in[12];
  const float* bf1  = (const float*)d_in[13];
  const float* W2   = (const float*)d_in[14];
  const float* bf2  = (const float*)d_in[15];
  const float* g2   = (const float*)d_in[16];
  const float* b2   = (const float*)d_in[17];

  const size_t SD = (size_t)ROWS * DDIM;   // 3145728

  char* ws = (char*)d_ws;
  short* hb = (short*)ws;  ws += SD * 2;                         //  6.29 MB
  short* ab = (short*)ws;  ws += SD * 2;                         //  6.29 MB
  short* R1 = (short*)ws;  ws += (size_t)ROWS * DFF * 2;         // 25.17 MB
  short* WB = (short*)ws;  ws += (size_t)(4 * WDD + 2 * WFD) * 2; // 14.16 MB
  short* P0 = (short*)ws;  ws += SD * 2;                         //  6.29 MB
  short* P1 = (short*)ws;                                        //  6.29 MB

  short* Qb = R1;
  short* Kb = R1 + SD;
  short* Vb = R1 + 2 * SD;
  short* Cb = R1 + 3 * SD;

  // x -> bf16 residual
  xconv_kernel<<<dim3((int)(SD / 8 / 256)), 256, 0, stream>>>(x, hb);

  for (int l = 0; l < NLAYER; l++) {
    // all six weight tensors of layer l in ONE launch
    {
      W6 w{};
      w.src[0] = Wq + (size_t)l * WDD;
      w.src[1] = Wk + (size_t)l * WDD;
      w.src[2] = Wv + (size_t)l * WDD;
      w.src[3] = Wo + (size_t)l * WDD;
      w.src[4] = W1 + (size_t)l * WFD;
      w.src[5] = W2 + (size_t)l * WFD;
      w.wb = WB;
      wconv6_kernel<<<dim3(1152, 6), 256, 0, stream>>>(w);
    }

    // QKV (fused via grid.z), reads hb
    {
      GemmB g{};
      g.W0 = WB;           g.b0 = bq + (size_t)l * DDIM; g.o0 = Qb;
      g.W1 = WB + WDD;     g.b1 = bk + (size_t)l * DDIM; g.o1 = Kb;
      g.W2 = WB + 2 * WDD; g.b2 = bv + (size_t)l * DDIM; g.o2 = Vb;
      gemm_bt<1, 128, 0><<<dim3(32, 6, 3), 256, 0, stream>>>(hb, g, ROWS, DDIM, DDIM, DDIM);
    }

    // attention: ctx -> q3
    attn_kernel<<<dim3(NB * NH, 4), 256, 0, stream>>>(Qb, Kb, Vb, mask, Cb);

    // O projection, split-K2 -> P0,P1 (768 blocks = 3/CU; bf16 partials)
    {
      GemmB g{};
      g.W0 = WB + 3 * WDD; g.b0 = bo; g.o0 = P0; g.o1 = P1;
      gemm_bt<3, 64, 1><<<dim3(64, 6, 2), 256, 0, stream>>>(Cb, g, ROWS, DDIM, DDIM, DDIM / 2);
    }

    // LN1 = reduce(P0+P1) + bias + LN(hb + .) -> ab (bf16)
    ln_red_kernel<0><<<dim3(ROWS / 4), 256, 0, stream>>>(hb, P0, P1,
                                                         bo + (size_t)l * DDIM,
                                                         g1 + (size_t)l * DDIM, b1 + (size_t)l * DDIM,
                                                         ab, nullptr);

    // FFN1 (bf16 + ReLU) -> R1 full, reads ab
    {
      GemmB g{};
      g.W0 = WB + 4 * WDD; g.b0 = bf1 + (size_t)l * DFF; g.o0 = R1;
      gemm_bt<2, 128, 0><<<dim3(32, 24, 1), 256, 0, stream>>>(ab, g, ROWS, DFF, DDIM, DDIM);
    }

    // FFN2, split-K2 -> P0,P1 (768 blocks, 48 steps each; bf16 partials)
    {
      GemmB g{};
      g.W0 = WB + 4 * WDD + WFD; g.b0 = bf2; g.o0 = P0; g.o1 = P1;
      gemm_bt<3, 64, 1><<<dim3(64, 6, 2), 256, 0, stream>>>(R1, g, ROWS, DDIM, DFF, DFF / 2);
    }

    // LN2 = reduce(P0+P1) + bias + LN(ab + .) -> hb (bf16); final also fp32
    if (l == NLAYER - 1)
      ln_red_kernel<1><<<dim3(ROWS / 4), 256, 0, stream>>>(ab, P0, P1,
                                                           bf2 + (size_t)l * DDIM,
                                                           g2 + (size_t)l * DDIM, b2 + (size_t)l * DDIM,
                                                           hb, (float*)d_out);
    else
      ln_red_kernel<0><<<dim3(ROWS / 4), 256, 0, stream>>>(ab, P0, P1,
                                                           bf2 + (size_t)l * DDIM,
                                                           g2 + (size_t)l * DDIM, b2 + (size_t)l * DDIM,
                                                           hb, nullptr);
  }
}